// Round 16
// baseline (543.765 us; speedup 1.0000x reference)
//
#include <hip/hip_runtime.h>
#include <math.h>

#define DD 768
#define NH 4
#define HDIM 192
#define BBATCH 8
#define NSEQ 1024
#define TLEN 2000
#define SLOT 6291456   // 8192*768 elements
#define XROW 256256    // per-batch rows in padded conv buffer: 2002*128

typedef _Float16 h16;
typedef _Float16 half8v __attribute__((ext_vector_type(8)));
typedef _Float16 half4v __attribute__((ext_vector_type(4)));
typedef float f32x4 __attribute__((ext_vector_type(4)));

__device__ __forceinline__ float gelu_f(float x){
  return 0.5f * x * (1.0f + erff(x * 0.70710678118654752440f));
}
__device__ __forceinline__ float wave_sum(float v){
  #pragma unroll
  for (int off = 32; off; off >>= 1) v += __shfl_xor(v, off);
  return v;
}
__device__ __forceinline__ float wave_max(float v){
  #pragma unroll
  for (int off = 32; off; off >>= 1) v = fmaxf(v, __shfl_xor(v, off));
  return v;
}
__device__ __forceinline__ void gload16(const h16* g, h16* l){
  __builtin_amdgcn_global_load_lds(
      (const __attribute__((address_space(1))) void*)g,
      (__attribute__((address_space(3))) void*)l, 16, 0, 0);
}
// m204 bijective XCD remap
__device__ __forceinline__ int xcd_remap(int orig, int nwg){
  int q = nwg >> 3, r = nwg & 7;
  int xcd = orig & 7, idx = orig >> 3;
  return (xcd < r ? xcd * (q + 1) : r * (q + 1) + (xcd - r) * q) + idx;
}

// ---------------- merged f32 -> f16 cast (5 segments, 1 dispatch) ------------
struct CastArgs {
  const float* s[5];
  h16* d[5];
  int cum[6];
};
__global__ __launch_bounds__(256) void k_cast5(CastArgs a, int total){
  int i = blockIdx.x * 256 + threadIdx.x;
  if (i >= total) return;
  int seg = 0;
  #pragma unroll
  for (int t = 1; t < 5; ++t) seg += (i >= a.cum[t]);
  int off = i - a.cum[seg];
  a.d[seg][off] = (h16)a.s[seg][off];
}

// ------ conv2 weight cast + permute: (OC,IC,KH) ic-major -> kh-major --------
__global__ __launch_bounds__(256) void k_castc2(const float* __restrict__ s,
    h16* __restrict__ d){
  int i = blockIdx.x * 256 + threadIdx.x;
  if (i >= 294912) return;
  int oc = i / 384, rem = i % 384;
  int ic = rem / 3, kh = rem % 3;
  d[oc * 384 + kh * 128 + ic] = (h16)s[i];
}

// ------ conv1 (20->128, k=3) + bn + gelu -> padded f16 X[b][2002][128] -------
__global__ __launch_bounds__(256) void k_conv1t(const float* __restrict__ cqcc,
    const float* __restrict__ w, const float* __restrict__ bias,
    const float* __restrict__ g, const float* __restrict__ be,
    const float* __restrict__ mm, const float* __restrict__ vv,
    h16* __restrict__ X){
  __shared__ float xs[20][258];
  __shared__ float wsm[32*60];
  const int t0 = blockIdx.x * 256;
  const int ocg = blockIdx.y, b = blockIdx.z;
  const int tid = threadIdx.x;
  for (int idx = tid; idx < 20*258; idx += 256){
    int ic = idx / 258, tt = idx % 258;
    int t = t0 + tt - 1;
    xs[ic][tt] = (t >= 0 && t < TLEN) ? cqcc[((size_t)b*20 + ic)*TLEN + t] : 0.f;
  }
  for (int idx = tid; idx < 32*60; idx += 256)
    wsm[idx] = w[ocg*32*60 + idx];
  __syncthreads();
  int t = t0 + tid;
  if (t >= TLEN) return;
  float acc[32] = {};
  for (int ic = 0; ic < 20; ++ic){
    float x0 = xs[ic][tid], x1v = xs[ic][tid+1], x2v = xs[ic][tid+2];
    #pragma unroll
    for (int oc = 0; oc < 32; ++oc){
      const float* wp = &wsm[(oc*20 + ic)*3];
      acc[oc] += wp[0]*x0 + wp[1]*x1v + wp[2]*x2v;
    }
  }
  h16* dst = X + (size_t)b*XROW + (size_t)(t+1)*128 + ocg*32;
  #pragma unroll 4
  for (int oc = 0; oc < 32; ++oc){
    int c = ocg*32 + oc;
    float s = rsqrtf(vv[c] + 1e-5f) * g[c];
    float val = (acc[oc] + bias[c] - mm[c]) * s + be[c];
    dst[oc] = (h16)gelu_f(val);
  }
  if (t == 0){
    h16* z = X + (size_t)b*XROW + ocg*32;
    #pragma unroll
    for (int oc = 0; oc < 32; ++oc) z[oc] = (h16)0.f;
  }
  if (t == TLEN-1){
    h16* z = X + (size_t)b*XROW + (size_t)2001*128 + ocg*32;
    #pragma unroll
    for (int oc = 0; oc < 32; ++oc) z[oc] = (h16)0.f;
  }
}

// ---------------- BN epilogue constants for conv2 ----------------
__global__ void k_bnprep(const float* __restrict__ cb, const float* __restrict__ g,
    const float* __restrict__ be, const float* __restrict__ m,
    const float* __restrict__ v, float* __restrict__ sc, float* __restrict__ off){
  int i = blockIdx.x * 256 + threadIdx.x;
  if (i >= DD) return;
  float s = g[i] * rsqrtf(v[i] + 1e-5f);
  sc[i] = s;
  off[i] = (cb[i] - m[i]) * s + be[i];
}

// ------- fused interp(2000->1024)+pos + dual LN (h16 input) -----------------
__global__ __launch_bounds__(256) void k_interp_ln(const h16* __restrict__ x2,
    const float* __restrict__ pe,
    const float* __restrict__ g1, const float* __restrict__ b1, h16* __restrict__ o1,
    const float* __restrict__ g2, const float* __restrict__ b2, h16* __restrict__ o2){
  __shared__ float ss[4], sqq[4];
  int row = blockIdx.x, tid = threadIdx.x;
  int b = row >> 10, i = row & 1023;
  float p = (i + 0.5f) * ((float)TLEN / (float)NSEQ) - 0.5f;
  p = fminf(fmaxf(p, 0.f), (float)(TLEN - 1));
  int lo = (int)floorf(p);
  int hi = min(lo + 1, TLEN - 1);
  float w = p - (float)lo;
  const h16* blo = x2 + ((size_t)b * TLEN + lo) * DD;
  const h16* bhi = x2 + ((size_t)b * TLEN + hi) * DD;
  const float* per = pe + (size_t)i * DD;
  float v[3]; float s = 0.f, sq = 0.f;
  #pragma unroll
  for (int j = 0; j < 3; ++j){
    int d = j * 256 + tid;
    float x = (float)blo[d] * (1.f - w) + (float)bhi[d] * w + per[d];
    v[j] = x; s += x; sq += x * x;
  }
  s = wave_sum(s); sq = wave_sum(sq);
  int wv = tid >> 6;
  if ((tid & 63) == 0){ ss[wv] = s; sqq[wv] = sq; }
  __syncthreads();
  s  = ss[0] + ss[1] + ss[2] + ss[3];
  sq = sqq[0] + sqq[1] + sqq[2] + sqq[3];
  float mean = s * (1.f / DD);
  float var  = sq * (1.f / DD) - mean * mean;
  float r = rsqrtf(var + 1e-5f);
  #pragma unroll
  for (int j = 0; j < 3; ++j){
    int d = j * 256 + tid;
    float xn = (v[j] - mean) * r;
    o1[(size_t)row * DD + d] = (h16)(xn * g1[d] + b1[d]);
    o2[(size_t)row * DD + d] = (h16)(xn * g2[d] + b2[d]);
  }
}

// ------- fused w2v+pos + dual LN --------------------------------------------
__global__ __launch_bounds__(256) void k_addpos_ln(const float* __restrict__ xin,
    const float* __restrict__ pe,
    const float* __restrict__ g1, const float* __restrict__ b1, h16* __restrict__ o1,
    const float* __restrict__ g2, const float* __restrict__ b2, h16* __restrict__ o2){
  __shared__ float ss[4], sqq[4];
  int row = blockIdx.x, tid = threadIdx.x;
  int i = row & 1023;
  const float* ip = xin + (size_t)row * DD;
  const float* per = pe + (size_t)i * DD;
  float v[3]; float s = 0.f, sq = 0.f;
  #pragma unroll
  for (int j = 0; j < 3; ++j){
    int d = j * 256 + tid;
    float x = ip[d] + per[d];
    v[j] = x; s += x; sq += x * x;
  }
  s = wave_sum(s); sq = wave_sum(sq);
  int wv = tid >> 6;
  if ((tid & 63) == 0){ ss[wv] = s; sqq[wv] = sq; }
  __syncthreads();
  s  = ss[0] + ss[1] + ss[2] + ss[3];
  sq = sqq[0] + sqq[1] + sqq[2] + sqq[3];
  float mean = s * (1.f / DD);
  float var  = sq * (1.f / DD) - mean * mean;
  float r = rsqrtf(var + 1e-5f);
  #pragma unroll
  for (int j = 0; j < 3; ++j){
    int d = j * 256 + tid;
    float xn = (v[j] - mean) * r;
    o1[(size_t)row * DD + d] = (h16)(xn * g1[d] + b1[d]);
    o2[(size_t)row * DD + d] = (h16)(xn * g2[d] + b2[d]);
  }
}

// ------- GAT layernorm: h16 state + f32 ctx add -> h16 (in-place safe) ------
__global__ __launch_bounds__(256) void k_lnH(const h16* __restrict__ in,
    const float* __restrict__ ctx, const float* __restrict__ g,
    const float* __restrict__ be, h16* __restrict__ out){
  __shared__ float ss[4], sqq[4];
  int row = blockIdx.x, tid = threadIdx.x;
  const h16* ip = in + (size_t)row * DD;
  int b = row >> 10;
  float v[3]; float s = 0.f, sq = 0.f;
  #pragma unroll
  for (int j = 0; j < 3; ++j){
    int d = j * 256 + tid;
    float x = (float)ip[d] + ctx[b * DD + d];
    v[j] = x; s += x; sq += x * x;
  }
  s = wave_sum(s); sq = wave_sum(sq);
  int w = tid >> 6;
  if ((tid & 63) == 0){ ss[w] = s; sqq[w] = sq; }
  __syncthreads();
  s  = ss[0] + ss[1] + ss[2] + ss[3];
  sq = sqq[0] + sqq[1] + sqq[2] + sqq[3];
  float mean = s * (1.f / DD);
  float var  = sq * (1.f / DD) - mean * mean;
  float r = rsqrtf(var + 1e-5f);
  #pragma unroll
  for (int j = 0; j < 3; ++j){
    int d = j * 256 + tid;
    out[(size_t)row * DD + d] = (h16)((v[j] - mean) * r * g[d] + be[d]);
  }
}

// ---------------- xh = a + b (f16, vectorized) -------------------------------
__global__ __launch_bounds__(256) void k_addh(const h16* __restrict__ a,
    const h16* __restrict__ b, h16* __restrict__ o, int n8){
  int i = blockIdx.x * 256 + threadIdx.x;
  if (i < n8){
    half8v x = ((const half8v*)a)[i];
    half8v y = ((const half8v*)b)[i];
    ((half8v*)o)[i] = x + y;
  }
}

// ======== pipelined GEMM mainloop (BM=128, BN=128, BK=64) ========
#define GEMM_MAINLOOP(Abase, lda, Wbase, ldw, Kdim)                          \
  auto stage = [&](int buf, int kt){                                         \
    _Pragma("unroll")                                                        \
    for (int i = 0; i < 4; ++i){                                             \
      int p = i*256 + tid; int row = p >> 3; int ch = (p & 7) ^ (row & 7);   \
      gload16(Abase + (size_t)(m0+row)*lda + kt + ch*8, &Als[buf][p*8]);     \
    }                                                                        \
    _Pragma("unroll")                                                        \
    for (int i = 0; i < 4; ++i){                                             \
      int p = i*256 + tid; int row = p >> 3; int ch = (p & 7) ^ (row & 7);   \
      gload16(Wbase + (size_t)(n0+row)*ldw + kt + ch*8, &Bls[buf][p*8]);     \
    }                                                                        \
  };                                                                         \
  stage(0, 0);                                                               \
  const int nk = Kdim >> 6;                                                  \
  for (int t = 0; t < nk; ++t){                                              \
    const int cur = t & 1;                                                   \
    if (t + 1 < nk){                                                         \
      stage(cur ^ 1, (t + 1) << 6);                                          \
      asm volatile("s_waitcnt vmcnt(8)" ::: "memory");                       \
    } else {                                                                 \
      asm volatile("s_waitcnt vmcnt(0)" ::: "memory");                       \
    }                                                                        \
    __builtin_amdgcn_s_barrier();                                            \
    __builtin_amdgcn_sched_barrier(0);                                       \
    __builtin_amdgcn_s_setprio(1);                                           \
    _Pragma("unroll")                                                        \
    for (int kk = 0; kk < 2; ++kk){                                          \
      half8v af[4], bf[4];                                                   \
      _Pragma("unroll")                                                      \
      for (int mi = 0; mi < 4; ++mi){                                        \
        int row = wr*64 + mi*16 + lr;                                        \
        int chp = (kk*4 + lg) ^ (row & 7);                                   \
        af[mi] = *(const half8v*)&Als[cur][row*64 + chp*8];                  \
      }                                                                      \
      _Pragma("unroll")                                                      \
      for (int ni = 0; ni < 4; ++ni){                                        \
        int row = wc*64 + ni*16 + lr;                                        \
        int chp = (kk*4 + lg) ^ (row & 7);                                   \
        bf[ni] = *(const half8v*)&Bls[cur][row*64 + chp*8];                  \
      }                                                                      \
      _Pragma("unroll")                                                      \
      for (int mi = 0; mi < 4; ++mi)                                         \
        _Pragma("unroll")                                                    \
        for (int ni = 0; ni < 4; ++ni)                                       \
          acc[mi][ni] = __builtin_amdgcn_mfma_f32_16x16x32_f16(              \
              af[mi], bf[ni], acc[mi][ni], 0, 0, 0);                         \
    }                                                                        \
    __builtin_amdgcn_s_setprio(0);                                           \
    asm volatile("s_waitcnt lgkmcnt(0)" ::: "memory");                       \
    __builtin_amdgcn_sched_barrier(0);                                       \
    __builtin_amdgcn_s_barrier();                                            \
  }

// ---------------- general GEMM (GAT path): fused row-dot --------------------
__global__ __launch_bounds__(256) void k_gemm_h(
    const h16* __restrict__ A, const h16* __restrict__ W,
    int lda, int ldw, int ldc, int K,
    const float* __restrict__ bias,
    h16* __restrict__ outh,
    const float* __restrict__ rdw, float* __restrict__ rdpart)
{
  __shared__ h16 Als[2][128*64];
  __shared__ h16 Bls[2][128*64];
  const int tid = threadIdx.x;
  const int gx = gridDim.x, gy = gridDim.y;
  const int wg = xcd_remap(blockIdx.x + gx * blockIdx.y, gx * gy);
  const int nidx = wg % gx;
  const int n0 = nidx * 128, m0 = (wg / gx) * 128;
  const int lane = tid & 63, wid = tid >> 6;
  const int wr = wid >> 1, wc = wid & 1;
  const int lr = lane & 15, lg = lane >> 4;
  f32x4 acc[4][4] = {};
  GEMM_MAINLOOP(A, lda, W, ldw, K)
  float rd[4][4] = {};
  #pragma unroll
  for (int mi = 0; mi < 4; ++mi){
    #pragma unroll
    for (int ni = 0; ni < 4; ++ni){
      int col = n0 + wc*64 + ni*16 + lr;
      int rowb = m0 + wr*64 + mi*16 + lg*4;
      float cb = bias[col];
      float aw = rdw ? rdw[col] : 0.f;
      #pragma unroll
      for (int r = 0; r < 4; ++r){
        size_t idx = (size_t)(rowb + r) * ldc + col;
        float v = acc[mi][ni][r] + cb;
        outh[idx] = (h16)v;
        if (rdw) rd[mi][r] += v * aw;
      }
    }
  }
  if (rdw){
    #pragma unroll
    for (int mi = 0; mi < 4; ++mi){
      #pragma unroll
      for (int r = 0; r < 4; ++r){
        float p = rd[mi][r];
        #pragma unroll
        for (int o = 1; o < 16; o <<= 1) p += __shfl_xor(p, o);
        if (lr == 0){
          int row = m0 + wr*64 + mi*16 + lg*4 + r;
          rdpart[(size_t)row * 12 + nidx*2 + wc] = p;
        }
      }
    }
  }
}

// ---------------- batched 2-way out-projection GEMM --------------------------
__global__ __launch_bounds__(256) void k_gemmop(
    const h16* __restrict__ A0, const h16* __restrict__ A1,
    const h16* __restrict__ W0, const h16* __restrict__ W1,
    const float* __restrict__ bb0, const float* __restrict__ bb1,
    h16* __restrict__ C0, h16* __restrict__ C1)
{
  __shared__ h16 Als[2][128*64];
  __shared__ h16 Bls[2][128*64];
  const int tid = threadIdx.x;
  const int gx = gridDim.x, gy = gridDim.y;   // 6, 64
  const int nwg = gx * gy * 2;
  const int wg = xcd_remap(blockIdx.x + gx*(blockIdx.y + gy*blockIdx.z), nwg);
  const int n0 = (wg % gx) * 128;
  const int m0 = ((wg / gx) % gy) * 128;
  const int bz = wg / (gx * gy);
  const h16* A = bz ? A1 : A0;
  const h16* W = bz ? W1 : W0;
  const float* bias = bz ? bb1 : bb0;
  h16* C = bz ? C1 : C0;
  const int lane = tid & 63, wid = tid >> 6;
  const int wr = wid >> 1, wc = wid & 1;
  const int lr = lane & 15, lg = lane >> 4;
  f32x4 acc[4][4] = {};
  GEMM_MAINLOOP(A, DD, W, DD, DD)
  #pragma unroll
  for (int mi = 0; mi < 4; ++mi){
    #pragma unroll
    for (int ni = 0; ni < 4; ++ni){
      int col = n0 + wc*64 + ni*16 + lr;
      int rowb = m0 + wr*64 + mi*16 + lg*4;
      float cb = bias[col];
      #pragma unroll
      for (int r = 0; r < 4; ++r)
        C[(size_t)(rowb + r) * DD + col] = (h16)(acc[mi][ni][r] + cb);
    }
  }
}

// ------ conv2 as overlapping-window GEMM over padded X (no im2col) ----------
__global__ __launch_bounds__(256) void k_conv2g(
    const h16* __restrict__ X, const h16* __restrict__ W,
    const float* __restrict__ sc, const float* __restrict__ off,
    h16* __restrict__ out)
{
  __shared__ h16 Als[2][128*64];
  __shared__ h16 Bls[2][128*64];
  const int tid = threadIdx.x;
  const int gx = gridDim.x, gy = gridDim.y;   // 6, 128
  const int wg = xcd_remap(blockIdx.x + gx * blockIdx.y, gx * gy);
  const int n0 = (wg % gx) * 128, m0 = (wg / gx) * 128;
  const int lane = tid & 63, wid = tid >> 6;
  const int wr = wid >> 1, wc = wid & 1;
  const int lr = lane & 15, lg = lane >> 4;
  f32x4 acc[4][4] = {};
  auto stage = [&](int buf, int kt){
    #pragma unroll
    for (int i = 0; i < 4; ++i){
      int p = i*256 + tid; int row = p >> 3; int ch = (p & 7) ^ (row & 7);
      int rm = m0 + row, b = rm >> 11, t = rm & 2047;
      gload16(X + (size_t)b*XROW + (size_t)t*128 + kt + ch*8, &Als[buf][p*8]);
    }
    #pragma unroll
    for (int i = 0; i < 4; ++i){
      int p = i*256 + tid; int row = p >> 3; int ch = (p & 7) ^ (row & 7);
      gload16(W + (size_t)(n0+row)*384 + kt + ch*8, &Bls[buf][p*8]);
    }
  };
  stage(0, 0);
  const int nk = 6;  // K=384
  for (int t = 0; t < nk; ++t){
    const int cur = t & 1;
    if (t + 1 < nk){
      stage(cur ^ 1, (t + 1) << 6);
      asm volatile("s_waitcnt vmcnt(8)" ::: "memory");
    } else {
      asm volatile("s_waitcnt vmcnt(0)" ::: "memory");
    }
    __builtin_amdgcn_s_barrier();
    __builtin_amdgcn_sched_barrier(0);
    __builtin_amdgcn_s_setprio(1);
    #pragma unroll
    for (int kk = 0; kk < 2; ++kk){
      half8v af[4], bf[4];
      #pragma unroll
      for (int mi = 0; mi < 4; ++mi){
        int row = wr*64 + mi*16 + lr;
        int chp = (kk*4 + lg) ^ (row & 7);
        af[mi] = *(const half8v*)&Als[cur][row*64 + chp*8];
      }
      #pragma unroll
      for (int ni = 0; ni < 4; ++ni){
        int row = wc*64 + ni*16 + lr;
        int chp = (kk*4 + lg) ^ (row & 7);
        bf[ni] = *(const half8v*)&Bls[cur][row*64 + chp*8];
      }
      #pragma unroll
      for (int mi = 0; mi < 4; ++mi)
        #pragma unroll
        for (int ni = 0; ni < 4; ++ni)
          acc[mi][ni] = __builtin_amdgcn_mfma_f32_16x16x32_f16(
              af[mi], bf[ni], acc[mi][ni], 0, 0, 0);
    }
    __builtin_amdgcn_s_setprio(0);
    asm volatile("s_waitcnt lgkmcnt(0)" ::: "memory");
    __builtin_amdgcn_sched_barrier(0);
    __builtin_amdgcn_s_barrier();
  }
  #pragma unroll
  for (int mi = 0; mi < 4; ++mi){
    #pragma unroll
    for (int ni = 0; ni < 4; ++ni){
      int col = n0 + wc*64 + ni*16 + lr;
      int rowb = m0 + wr*64 + mi*16 + lg*4;
      #pragma unroll
      for (int r = 0; r < 4; ++r){
        int rm = rowb + r, b = rm >> 11, t = rm & 2047;
        if (t < TLEN){
          float v = acc[mi][ni][r] * sc[col] + off[col];
          out[((size_t)b*TLEN + t)*DD + col] = (h16)gelu_f(v);
        }
      }
    }
  }
}

// ---------------- batched 6-way QKV projection GEMM --------------------------
__global__ __launch_bounds__(256) void k_gemm6(
    const h16* __restrict__ Lall, const h16* __restrict__ w6,
    const float* __restrict__ b1, const float* __restrict__ b2,
    h16* __restrict__ qkv6)
{
  __shared__ h16 Als[2][128*64];
  __shared__ h16 Bls[2][128*64];
  const int tid = threadIdx.x;
  const int gx = gridDim.x, gy = gridDim.y;   // 6, 64
  const int nwg = gx * gy * 6;
  const int wg = xcd_remap(blockIdx.x + gx*(blockIdx.y + gy*blockIdx.z), nwg);
  const int n0 = (wg % gx) * 128;
  const int m0 = ((wg / gx) % gy) * 128;
  const int bz = wg / (gx * gy);
  const int aidx = (1468 >> (2*bz)) & 3;      // {0,3,3,2,1,1}
  const h16* A = Lall + (size_t)aidx * SLOT;
  const h16* W = w6 + (size_t)bz * 589824;
  const float* bias = (bz < 3 ? b1 + bz*DD : b2 + (bz-3)*DD);
  h16* C = qkv6 + (size_t)bz * SLOT;
  const int lane = tid & 63, wid = tid >> 6;
  const int wr = wid >> 1, wc = wid & 1;
  const int lr = lane & 15, lg = lane >> 4;
  f32x4 acc[4][4] = {};
  GEMM_MAINLOOP(A, DD, W, DD, DD)
  #pragma unroll
  for (int mi = 0; mi < 4; ++mi){
    #pragma unroll
    for (int ni = 0; ni < 4; ++ni){
      int col = n0 + wc*64 + ni*16 + lr;
      int rowb = m0 + wr*64 + mi*16 + lg*4;
      float cb = bias[col];
      #pragma unroll
      for (int r = 0; r < 4; ++r)
        C[(size_t)(rowb + r) * DD + col] = (h16)(acc[mi][ni][r] + cb);
    }
  }
}

// ------- merged V transpose: z = which*32 + bh ------------------------------
__global__ __launch_bounds__(256) void k_trV(const h16* __restrict__ V0,
    const h16* __restrict__ V1, h16* __restrict__ VT0, h16* __restrict__ VT1){
  __shared__ h16 tile[64*64];
  const int zz = blockIdx.z;
  const int which = zz >> 5, bh = zz & 31;
  const int b = bh >> 2, h = bh & 3;
  const h16* Vh = which ? V1 : V0;
  h16* VT = which ? VT1 : VT0;
  const int q0 = blockIdx.x * 64, d0 = blockIdx.y * 64;
  const int t = threadIdx.x;
  {
    int qq = t >> 2, ds = (t & 3) * 16;
    const h16* src = Vh + ((size_t)b*NSEQ + q0 + qq)*DD + h*HDIM + d0 + ds;
    half8v v0 = *(const half8v*)src;
    half8v v1 = *(const half8v*)(src + 8);
    int c0 = (ds >> 3) ^ (qq & 7), c1 = ((ds >> 3) + 1) ^ (qq & 7);
    *(half8v*)&tile[qq*64 + c0*8] = v0;
    *(half8v*)&tile[qq*64 + c1*8] = v1;
  }
  __syncthreads();
  {
    int dd = t >> 2, qs = (t & 3) * 16;
    half8v o0, o1;
    #pragma unroll
    for (int j = 0; j < 8; ++j){
      int q = qs + j, q2 = qs + 8 + j;
      o0[j] = tile[q*64  + (((dd>>3) ^ (q&7))*8)  + (dd & 7)];
      o1[j] = tile[q2*64 + (((dd>>3) ^ (q2&7))*8) + (dd & 7)];
    }
    h16* dst = VT + (size_t)bh*HDIM*NSEQ + (size_t)(d0+dd)*NSEQ + q0 + qs;
    *(half8v*)dst = o0;
    *(half8v*)(dst + 8) = o1;
  }
}

// ------- merged flash attention: prescaled-Q exp2, ones-column l -------------
__global__ __launch_bounds__(256, 3) void k_flash(
    const h16* __restrict__ Q0, const h16* __restrict__ K0,
    const h16* __restrict__ T0, h16* __restrict__ O0,
    const h16* __restrict__ Q1, const h16* __restrict__ K1,
    const h16* __restrict__ T1, h16* __restrict__ O1){
  __shared__ h16 Ks[2][32*192];
  __shared__ h16 Vs[2][192*32];
  __shared__ h16 Ps[4][16*32];
  const int tid = threadIdx.x;
  const int bh = blockIdx.x, qt = blockIdx.y, which = blockIdx.z;
  const int b = bh >> 2, h = bh & 3;
  const int q0 = qt * 64;
  const h16* Qp = which ? Q1 : Q0;
  const h16* Kp = which ? K1 : K0;
  const h16* VTp = which ? T1 : T0;
  h16* Op = which ? O1 : O0;
  const h16* Qg = Qp + (size_t)b*NSEQ*DD + h*HDIM;
  const h16* Kg = Kp + (size_t)b*NSEQ*DD + h*HDIM;
  const h16* Vg = VTp + (size_t)bh*HDIM*NSEQ;
  const int lane = tid & 63, wid = tid >> 6;
  const int lr = lane & 15, lg = lane >> 4;
  const float SC2 = 0.07216878364870322f * 1.4426950408889634f;  // /sqrt(192)*log2e
  half8v qf[6];
  {
    int qrow = q0 + wid*16 + lr;
    const h16 qs2 = (h16)SC2;
    #pragma unroll
    for (int ks = 0; ks < 6; ++ks){
      half8v qv = *(const half8v*)(Qg + (size_t)qrow*DD + ks*32 + lg*8);
      #pragma unroll
      for (int j = 0; j < 8; ++j) qv[j] = qv[j] * qs2;   // pre-scale: S in log2 units
      qf[ks] = qv;
    }
  }
  auto stageK = [&](int buf, int k0){
    #pragma unroll
    for (int i = 0; i < 3; ++i){
      int p = i*256 + tid;
      int row = p / 24, chp = p % 24;
      int ch = chp ^ (row & 7);
      gload16(Kg + (size_t)(k0+row)*DD + ch*8, &Ks[buf][p*8]);
    }
  };
  auto stageV = [&](int buf, int k0){
    #pragma unroll
    for (int i = 0; i < 3; ++i){
      int p = i*256 + tid;
      int row = p >> 2, chp = p & 3;
      int ch = chp ^ ((row >> 1) & 3);
      gload16(Vg + (size_t)row*NSEQ + k0 + ch*8, &Vs[buf][p*8]);
    }
  };
  stageK(0, 0); stageV(0, 0);
  f32x4 oacc[12] = {};
  f32x4 osum = {0.f, 0.f, 0.f, 0.f};   // ones-column accumulator = per-row l
  float m2[4] = {-1e30f, -1e30f, -1e30f, -1e30f};  // running max, log2 domain
  half8v vone;
  #pragma unroll
  for (int j = 0; j < 8; ++j) vone[j] = (h16)1.f;
  for (int kt = 0; kt < 32; ++kt){
    const int cur = kt & 1;
    if (kt + 1 < 32){
      stageK(cur^1, (kt+1)*32); stageV(cur^1, (kt+1)*32);
      asm volatile("s_waitcnt vmcnt(6)" ::: "memory");
    } else {
      asm volatile("s_waitcnt vmcnt(0)" ::: "memory");
    }
    __builtin_amdgcn_s_barrier();
    __builtin_amdgcn_sched_barrier(0);
    f32x4 sacc[2] = {};
    __builtin_amdgcn_s_setprio(1);
    #pragma unroll
    for (int ks = 0; ks < 6; ++ks){
      #pragma unroll
      for (int t = 0; t < 2; ++t){
        int krow = t*16 + lr;
        int ch = (ks*4 + lg) ^ (krow & 7);
        half8v kf = *(const half8v*)&Ks[cur][krow*192 + ch*8];
        sacc[t] = __builtin_amdgcn_mfma_f32_16x16x32_f16(qf[ks], kf, sacc[t], 0, 0, 0);
      }
    }
    __builtin_amdgcn_s_setprio(0);
    // ballot-gated defer-max (sacc already in log2 units)
    float lmaxr[4];
    #pragma unroll
    for (int r = 0; r < 4; ++r) lmaxr[r] = fmaxf(sacc[0][r], sacc[1][r]);
    bool flag = false;
    #pragma unroll
    for (int r = 0; r < 4; ++r) flag |= (lmaxr[r] > m2[r] + 14.f);
    if (__ballot(flag)){
      float c[4];
      #pragma unroll
      for (int r = 0; r < 4; ++r){
        float mt = lmaxr[r];
        #pragma unroll
        for (int off = 1; off < 16; off <<= 1) mt = fmaxf(mt, __shfl_xor(mt, off));
        if (mt > m2[r]){ c[r] = exp2f(m2[r] - mt); m2[r] = mt; }
        else c[r] = 1.f;
      }
      #pragma unroll
      for (int dt = 0; dt < 12; ++dt){
        f32x4 o = oacc[dt];
        o[0] *= c[0]; o[1] *= c[1]; o[2] *= c[2]; o[3] *= c[3];
        oacc[dt] = o;
      }
      osum[0] *= c[0]; osum[1] *= c[1]; osum[2] *= c[2]; osum[3] *= c[3];
    }
    #pragma unroll
    for (int t = 0; t < 2; ++t){
      #pragma unroll
      for (int r = 0; r < 4; ++r){
        float p = exp2f(sacc[t][r] - m2[r]);
        int q = lg*4 + r, key = t*16 + lr;
        int ch = (t*2 + (lr>>3)) ^ ((q>>1) & 3);
        Ps[wid][q*32 + ch*8 + (key & 7)] = (h16)p;
      }
    }
    asm volatile("s_waitcnt lgkmcnt(0)" ::: "memory");   // own-wave P writes done
    __builtin_amdgcn_sched_barrier(0);
    {
      int pch = lg ^ ((lr >> 1) & 3);
      half8v pf = *(const half8v*)&Ps[wid][lr*32 + pch*8];
      __builtin_amdgcn_s_setprio(1);
      #pragma unroll
      for (int dt = 0; dt < 12; ++dt){
        int drow = dt*16 + lr;
        int vch = lg ^ ((drow >> 1) & 3);
        half8v vf = *(const half8v*)&Vs[cur][drow*32 + vch*8];
        oacc[dt] = __builtin_amdgcn_mfma_f32_16x16x32_f16(pf, vf, oacc[dt], 0, 0, 0);
      }
      osum = __builtin_amdgcn_mfma_f32_16x16x32_f16(pf, vone, osum, 0, 0, 0);
      __builtin_amdgcn_s_setprio(0);
    }
    asm volatile("s_waitcnt lgkmcnt(0)" ::: "memory");   // LDS reads of cur retired
    __builtin_amdgcn_sched_barrier(0);
    __builtin_amdgcn_s_barrier();                         // safe to overwrite cur
  }
  float inv[4];
  #pragma unroll
  for (int r = 0; r < 4; ++r) inv[r] = 1.0f / osum[r];
  h16* Og = Op + (size_t)b*NSEQ*DD + h*HDIM;
  #pragma unroll
  for (int dt = 0; dt < 12; ++dt){
    #pragma unroll
    for (int r = 0; r < 4; ++r){
      int q = q0 + wid*16 + lg*4 + r;
      Og[(size_t)q*DD + dt*16 + lr] = (h16)(oacc[dt][r] * inv[r]);
    }
  }
}

// -------- softmax over 1024 from 12-way row partials -> alpha ---------------
__global__ __launch_bounds__(256) void k_softmax12(const float* __restrict__ part,
    float* __restrict__ y){
  __shared__ float red[4];
  int b = blockIdx.x, tid = threadIdx.x;
  float v[4]; float mx = -1e30f;
  #pragma unroll
  for (int j = 0; j < 4; ++j){
    int i = j * 256 + tid;
    const float* p = part + (size_t)(b * NSEQ + i) * 12;
    float s = 0.f;
    #pragma unroll
    for (int k = 0; k < 12; ++k) s += p[k];
    v[j] = s; mx = fmaxf(mx, s);
  }
  mx = wave_max(mx);
  if ((tid & 63) == 0) red[tid >> 6] = mx;
  __syncthreads();
  mx = fmaxf(fmaxf(red[0], red[1]), fmaxf(red[2], red[3]));
  __syncthreads();
  float s = 0.f;
  #pragma unroll
  for (int j = 0; j < 4; ++j){ v[j] = __expf(v[j] - mx); s += v[j]; }
  s = wave_sum(s);
  if ((tid & 63) == 0) red[tid >> 6] = s;
  __syncthreads();
  s = red[0] + red[1] + red[2] + red[3];
  float inv = 1.0f / s;
  #pragma unroll
  for (int j = 0; j < 4; ++j) y[b * NSEQ + j * 256 + tid] = v[j] * inv;
}

__global__ __launch_bounds__(256) void k_ctx1(const float* __restrict__ alpha,
    const h16* __restrict__ h, float* __restrict__ part){
  int d = blockIdx.x * 256 + threadIdx.x;
  int b = blockIdx.y, pc = blockIdx.z;
  if (d >= DD) return;
  float acc = 0.f;
  const h16* hp = h + ((size_t)b * NSEQ + pc * 64) * DD + d;
  const float* ap = alpha + b * NSEQ + pc * 64;
  #pragma unroll 4
  for (int j = 0; j < 64; ++j) acc += ap[j] * (float)hp[(size_t)j * DD];
  part[(size_t)(b * 16 + pc) * DD + d] = acc;
}
__global__ __launch_bounds__(256) void k_ctx2(const float* __restrict__ part,
    float scale, float* __restrict__ ctx){
  int d = blockIdx.x * 256 + threadIdx.x;
  int b = blockIdx.y;
  if (d >= DD) return;
  float acc = 0.f;
  #pragma unroll
  for (int p = 0; p < 16; ++p) acc += part[(size_t)(b * 16 + p) * DD + d];
  ctx[b * DD + d] = acc * scale;
}

__global__ __launch_bounds__(256) void k_pool1(const h16* __restrict__ x,
    float* __restrict__ part){
  int d = blockIdx.x * 256 + threadIdx.x;
  int b = blockIdx.y, pc = blockIdx.z;
  if (d >= DD) return;
  float acc = 0.f;
  const h16* xp = x + ((size_t)b * NSEQ + pc * 64) * DD + d;
  #pragma unroll 4
  for (int j = 0; j < 64; ++j) acc += (float)xp[(size_t)j * DD];
  part[(size_t)(b * 16 + pc) * DD + d] = acc;
}

// classifier: consumes 16-way pool partials directly
__global__ __launch_bounds__(128) void k_clf(const float* __restrict__ part,
    const float* __restrict__ w1, const float* __restrict__ b1,
    const float* __restrict__ w2, const float* __restrict__ b2,
    float* __restrict__ out){
  __shared__ float pl[DD];
  __shared__ float h1[128];
  int b = blockIdx.x, tid = threadIdx.x;
  #pragma unroll
  for (int j = 0; j < 6; ++j){
    int d = j * 128 + tid;
    float acc = 0.f;
    #pragma unroll
    for (int p = 0; p < 16; ++p) acc += part[(size_t)(b * 16 + p) * DD + d];
    pl[d] = acc * (1.0f / NSEQ);
  }
  __syncthreads();
  float acc = b1[tid];
  const float* wp = w1 + (size_t)tid * DD;
  for (int d = 0; d < DD; ++d) acc += pl[d] * wp[d];
  h1[tid] = gelu_f(acc);
  __syncthreads();
  if (tid < 2){
    float o = b2[tid];
    const float* w2p = w2 + tid * 128;
    for (int c = 0; c < 128; ++c) o += h1[c] * w2p[c];
    out[b * 2 + tid] = o;
  }
}

// =========================== launcher ===========================
extern "C" void kernel_launch(void* const* d_in, const int* in_sizes, int n_in,
                              void* d_out, int out_size, void* d_ws, size_t ws_size,
                              hipStream_t stream){
  (void)in_sizes; (void)n_in; (void)out_size;
  const float* w2v      = (const float*)d_in[0];
  const float* cqcc     = (const float*)d_in[1];
  const float* conv1_w  = (const float*)d_in[2];
  const float* conv1_b  = (const float*)d_in[3];
  const float* bn1_g    = (const float*)d_in[4];
  const float* bn1_b    = (const float*)d_in[5];
  const float* bn1_m    = (const float*)d_in[6];
  const float* bn1_v    = (const float*)d_in[7];
  const float* conv2_w  = (const float*)d_in[8];
  const float* conv2_b  = (const float*)d_in[9];
  const float* bn2_g    = (const float*)d_in[10];
  const float* bn2_b    = (const float*)d_in[11];
  const float* bn2_m    = (const float*)d_in[12];
  const float* bn2_v    = (const float*)d_in[13];
  const float* pos_embed= (const float*)d_in[14];
  const float* lnq_g    = (const float*)d_in[15];
  const float* lnq_b    = (const float*)d_in[16];
  const float* lnkv_g   = (const float*)d_in[17];
  const float* lnkv_b   = (const float*)d_in[18];
  const float* a1_in_w  = (const float*)d_in[19];
  const float* a1_in_b  = (const float*)d_in[20];
  const float* a1_out_w = (const float*)d_in[21];
  const float* a1_out_b = (const float*)d_in[22];
  const float* a2_in_w  = (const float*)d_in[23];
  const float* a2_in_b  = (const float*)d_in[24];
  const float* a2_out_w = (const float*)d_in[25];
  const float* a2_out_b = (const float*)d_in[26];
  const float* gat_fc_w = (const float*)d_in[27];
  const float* gat_fc_b = (const float*)d_in[28];
  const float* gat_a_w  = (const float*)d_in[29];
  // d_in[30] gat_a_b: cancels in softmax over j — unused.
  const float* gln_g    = (const float*)d_in[31];
  const float* gln_b    = (const float*)d_in[32];
  const float* clf_w1   = (const float*)d_in[33];
  const float* clf_b1   = (const float*)d_in[34];
  const float* clf_w2   = (const float*)d_in[35];
  const float* clf_b2   = (const float*)d_in[36];

  char* wsp = (char*)d_ws;
  auto F = [&](size_t bytes){ char* p = wsp; wsp += (bytes + 255) & ~(size_t)255; return p; };
  h16* xh      = (h16*)F(12582912);       // GAT running state (f16)
  h16* Lall    = (h16*)F(4*12582912);     // LN slots 0..3; also conv X buffer
  h16* qkv6    = (h16*)F(6*12582912);     // Q1 K1 V1 Q2 K2 V2; also x2h f16
  h16* VT      = (h16*)F(12582912);
  h16* VT2     = (h16*)F(12582912);
  h16* o1h     = (h16*)F(12582912);
  h16* o2h     = (h16*)F(12582912);
  h16* w6      = (h16*)F(2*3538944);      // Wqkv1 | Wqkv2
  h16* w_a1out = (h16*)F(1179648);
  h16* w_a2out = (h16*)F(1179648);
  h16* w_gat   = (h16*)F(3538944);
  h16* w_c2    = (h16*)F(589824);
  float* scb   = (float*)F(3072);
  float* offb  = (float*)F(3072);
  float* alpha = (float*)F(32768);
  float* ctxb  = (float*)F(24576);
  float* partb = (float*)F(393216);       // rowdot 8192x12 f32 / ctx 8x16x768 f32
  if ((size_t)(wsp - (char*)d_ws) > ws_size) return;

  h16* X   = Lall;                        // padded conv buffer [8][2002][128]
  h16* x2h = qkv6;                        // conv2 out f16 (24.6 MB, slots 0-1)
  h16* hh  = qkv6;                        // GAT h (slot0, dead after outproj)

  const int NR = BBATCH * NSEQ;           // 8192

  // --- merged weight casts + conv2 permute-cast + bn prep ---
  {
    CastArgs ca;
    ca.s[0]=a1_in_w;  ca.d[0]=w6;            int n0=1769472;
    ca.s[1]=a2_in_w;  ca.d[1]=w6+1769472;    int n1=1769472;
    ca.s[2]=a1_out_w; ca.d[2]=w_a1out;       int n2=589824;
    ca.s[3]=a2_out_w; ca.d[3]=w_a2out;       int n3=589824;
    ca.s[4]=gat_fc_w; ca.d[4]=w_gat;         int n4=1769472;
    ca.cum[0]=0; ca.cum[1]=n0; ca.cum[2]=n0+n1; ca.cum[3]=n0+n1+n2;
    ca.cum[4]=n0+n1+n2+n3; ca.cum[5]=n0+n1+n2+n3+n4;
    int total = ca.cum[5];
    k_cast5<<<(total+255)/256, 256, 0, stream>>>(ca, total);
  }
  k_castc2<<<(294912+255)/256, 256, 0, stream>>>(conv2_w, w_c2);
  k_bnprep<<<3, 256, 0, stream>>>(conv2_b, bn2_g, bn2_b, bn2_m, bn2_v, scb, offb);

  // --- front-end convs (no im2col) ---
  k_conv1t<<<dim3(8, 4, BBATCH), 256, 0, stream>>>(cqcc, conv1_w, conv1_b,
      bn1_g, bn1_b, bn1_m, bn1_v, X);
  k_conv2g<<<dim3(6, 128), 256, 0, stream>>>(X, w_c2, scb, offb, x2h);

  // --- fused interp/addpos + dual LN (slots 0..3) ---
  k_interp_ln<<<NR, 256, 0, stream>>>(x2h, pos_embed,
      lnq_g, lnq_b, Lall, lnkv_g, lnkv_b, Lall + SLOT);
  k_addpos_ln<<<NR, 256, 0, stream>>>(w2v, pos_embed,
      lnq_g, lnq_b, Lall + 2*SLOT, lnkv_g, lnkv_b, Lall + 3*SLOT);

  // --- all six QKV projections in one dispatch ---
  k_gemm6<<<dim3(6, 64, 6), 256, 0, stream>>>(Lall, w6, a1_in_b, a2_in_b, qkv6);

  // ================= both MHAs, merged =================
  k_trV<<<dim3(16, 3, 64), 256, 0, stream>>>(qkv6 + 2*(size_t)SLOT,
      qkv6 + 5*(size_t)SLOT, VT, VT2);
  k_flash<<<dim3(32, 16, 2), 256, 0, stream>>>(
      qkv6, qkv6 + (size_t)SLOT, VT, qkv6,                        // MHA1: O1 -> slot0
      qkv6 + 3*(size_t)SLOT, qkv6 + 4*(size_t)SLOT, VT2,
      qkv6 + 3*(size_t)SLOT);                                     // MHA2: O2 -> slot3
  k_gemmop<<<dim3(6, 64, 2), 256, 0, stream>>>(
      qkv6, qkv6 + 3*(size_t)SLOT, w_a1out, w_a2out,
      a1_out_b, a2_out_b, o1h, o2h);
  k_addh<<<(NR*DD/8 + 255)/256, 256, 0, stream>>>(o1h, o2h, xh, NR*DD/8);

  // ================= GAT x3 (softmax over j collapses; rowdot fused) ========
  for (int l = 0; l < 3; ++l){
    k_gemm_h<<<dim3(6, 64), 256, 0, stream>>>(xh, w_gat + (size_t)l*589824,
        DD, DD, DD, DD, gat_fc_b + l*DD, hh, gat_a_w + l*2*DD + DD, partb);
    k_softmax12<<<BBATCH, 256, 0, stream>>>(partb, alpha);
    k_ctx1<<<dim3(3, BBATCH, 16), 256, 0, stream>>>(alpha, hh, partb);
    k_ctx2<<<dim3(3, BBATCH), 256, 0, stream>>>(partb, 1.0f, ctxb);
    k_lnH<<<NR, 256, 0, stream>>>(xh, ctxb, gln_g + l*DD, gln_b + l*DD, xh);
  }

  k_pool1<<<dim3(3, BBATCH, 16), 256, 0, stream>>>(xh, partb);
  k_clf<<<BBATCH, 128, 0, stream>>>(partb, clf_w1, clf_b1, clf_w2, clf_b2,
                                    (float*)d_out);
}

// Round 17
// 525.603 us; speedup vs baseline: 1.0346x; 1.0346x over previous
//
#include <hip/hip_runtime.h>
#include <math.h>

#define DD 768
#define NH 4
#define HDIM 192
#define BBATCH 8
#define NSEQ 1024
#define TLEN 2000
#define SLOT 6291456   // 8192*768 elements
#define XROW 256256    // per-batch rows in padded conv buffer: 2002*128

typedef _Float16 h16;
typedef _Float16 half8v __attribute__((ext_vector_type(8)));
typedef _Float16 half4v __attribute__((ext_vector_type(4)));
typedef float f32x4 __attribute__((ext_vector_type(4)));

__device__ __forceinline__ float gelu_f(float x){
  return 0.5f * x * (1.0f + erff(x * 0.70710678118654752440f));
}
__device__ __forceinline__ float wave_sum(float v){
  #pragma unroll
  for (int off = 32; off; off >>= 1) v += __shfl_xor(v, off);
  return v;
}
__device__ __forceinline__ float wave_max(float v){
  #pragma unroll
  for (int off = 32; off; off >>= 1) v = fmaxf(v, __shfl_xor(v, off));
  return v;
}
__device__ __forceinline__ void gload16(const h16* g, h16* l){
  __builtin_amdgcn_global_load_lds(
      (const __attribute__((address_space(1))) void*)g,
      (__attribute__((address_space(3))) void*)l, 16, 0, 0);
}
// m204 bijective XCD remap
__device__ __forceinline__ int xcd_remap(int orig, int nwg){
  int q = nwg >> 3, r = nwg & 7;
  int xcd = orig & 7, idx = orig >> 3;
  return (xcd < r ? xcd * (q + 1) : r * (q + 1) + (xcd - r) * q) + idx;
}

// ---------------- merged f32 -> f16 cast (5 segments, 1 dispatch) ------------
struct CastArgs {
  const float* s[5];
  h16* d[5];
  int cum[6];
};
__global__ __launch_bounds__(256) void k_cast5(CastArgs a, int total){
  int i = blockIdx.x * 256 + threadIdx.x;
  if (i >= total) return;
  int seg = 0;
  #pragma unroll
  for (int t = 1; t < 5; ++t) seg += (i >= a.cum[t]);
  int off = i - a.cum[seg];
  a.d[seg][off] = (h16)a.s[seg][off];
}

// ------ conv2 weight cast + permute: (OC,IC,KH) ic-major -> kh-major --------
__global__ __launch_bounds__(256) void k_castc2(const float* __restrict__ s,
    h16* __restrict__ d){
  int i = blockIdx.x * 256 + threadIdx.x;
  if (i >= 294912) return;
  int oc = i / 384, rem = i % 384;
  int ic = rem / 3, kh = rem % 3;
  d[oc * 384 + kh * 128 + ic] = (h16)s[i];
}

// ------ conv1 (20->128, k=3) + bn + gelu -> padded f16 X[b][2002][128] -------
__global__ __launch_bounds__(256) void k_conv1t(const float* __restrict__ cqcc,
    const float* __restrict__ w, const float* __restrict__ bias,
    const float* __restrict__ g, const float* __restrict__ be,
    const float* __restrict__ mm, const float* __restrict__ vv,
    h16* __restrict__ X){
  __shared__ float xs[20][258];
  __shared__ float wsm[32*60];
  const int t0 = blockIdx.x * 256;
  const int ocg = blockIdx.y, b = blockIdx.z;
  const int tid = threadIdx.x;
  for (int idx = tid; idx < 20*258; idx += 256){
    int ic = idx / 258, tt = idx % 258;
    int t = t0 + tt - 1;
    xs[ic][tt] = (t >= 0 && t < TLEN) ? cqcc[((size_t)b*20 + ic)*TLEN + t] : 0.f;
  }
  for (int idx = tid; idx < 32*60; idx += 256)
    wsm[idx] = w[ocg*32*60 + idx];
  __syncthreads();
  int t = t0 + tid;
  if (t >= TLEN) return;
  float acc[32] = {};
  for (int ic = 0; ic < 20; ++ic){
    float x0 = xs[ic][tid], x1v = xs[ic][tid+1], x2v = xs[ic][tid+2];
    #pragma unroll
    for (int oc = 0; oc < 32; ++oc){
      const float* wp = &wsm[(oc*20 + ic)*3];
      acc[oc] += wp[0]*x0 + wp[1]*x1v + wp[2]*x2v;
    }
  }
  h16* dst = X + (size_t)b*XROW + (size_t)(t+1)*128 + ocg*32;
  #pragma unroll 4
  for (int oc = 0; oc < 32; ++oc){
    int c = ocg*32 + oc;
    float s = rsqrtf(vv[c] + 1e-5f) * g[c];
    float val = (acc[oc] + bias[c] - mm[c]) * s + be[c];
    dst[oc] = (h16)gelu_f(val);
  }
  if (t == 0){
    h16* z = X + (size_t)b*XROW + ocg*32;
    #pragma unroll
    for (int oc = 0; oc < 32; ++oc) z[oc] = (h16)0.f;
  }
  if (t == TLEN-1){
    h16* z = X + (size_t)b*XROW + (size_t)2001*128 + ocg*32;
    #pragma unroll
    for (int oc = 0; oc < 32; ++oc) z[oc] = (h16)0.f;
  }
}

// ---------------- BN epilogue constants for conv2 ----------------
__global__ void k_bnprep(const float* __restrict__ cb, const float* __restrict__ g,
    const float* __restrict__ be, const float* __restrict__ m,
    const float* __restrict__ v, float* __restrict__ sc, float* __restrict__ off){
  int i = blockIdx.x * 256 + threadIdx.x;
  if (i >= DD) return;
  float s = g[i] * rsqrtf(v[i] + 1e-5f);
  sc[i] = s;
  off[i] = (cb[i] - m[i]) * s + be[i];
}

// ------- fused interp(2000->1024)+pos + dual LN (h16 input) -----------------
__global__ __launch_bounds__(256) void k_interp_ln(const h16* __restrict__ x2,
    const float* __restrict__ pe,
    const float* __restrict__ g1, const float* __restrict__ b1, h16* __restrict__ o1,
    const float* __restrict__ g2, const float* __restrict__ b2, h16* __restrict__ o2){
  __shared__ float ss[4], sqq[4];
  int row = blockIdx.x, tid = threadIdx.x;
  int b = row >> 10, i = row & 1023;
  float p = (i + 0.5f) * ((float)TLEN / (float)NSEQ) - 0.5f;
  p = fminf(fmaxf(p, 0.f), (float)(TLEN - 1));
  int lo = (int)floorf(p);
  int hi = min(lo + 1, TLEN - 1);
  float w = p - (float)lo;
  const h16* blo = x2 + ((size_t)b * TLEN + lo) * DD;
  const h16* bhi = x2 + ((size_t)b * TLEN + hi) * DD;
  const float* per = pe + (size_t)i * DD;
  float v[3]; float s = 0.f, sq = 0.f;
  #pragma unroll
  for (int j = 0; j < 3; ++j){
    int d = j * 256 + tid;
    float x = (float)blo[d] * (1.f - w) + (float)bhi[d] * w + per[d];
    v[j] = x; s += x; sq += x * x;
  }
  s = wave_sum(s); sq = wave_sum(sq);
  int wv = tid >> 6;
  if ((tid & 63) == 0){ ss[wv] = s; sqq[wv] = sq; }
  __syncthreads();
  s  = ss[0] + ss[1] + ss[2] + ss[3];
  sq = sqq[0] + sqq[1] + sqq[2] + sqq[3];
  float mean = s * (1.f / DD);
  float var  = sq * (1.f / DD) - mean * mean;
  float r = rsqrtf(var + 1e-5f);
  #pragma unroll
  for (int j = 0; j < 3; ++j){
    int d = j * 256 + tid;
    float xn = (v[j] - mean) * r;
    o1[(size_t)row * DD + d] = (h16)(xn * g1[d] + b1[d]);
    o2[(size_t)row * DD + d] = (h16)(xn * g2[d] + b2[d]);
  }
}

// ------- fused w2v+pos + dual LN --------------------------------------------
__global__ __launch_bounds__(256) void k_addpos_ln(const float* __restrict__ xin,
    const float* __restrict__ pe,
    const float* __restrict__ g1, const float* __restrict__ b1, h16* __restrict__ o1,
    const float* __restrict__ g2, const float* __restrict__ b2, h16* __restrict__ o2){
  __shared__ float ss[4], sqq[4];
  int row = blockIdx.x, tid = threadIdx.x;
  int i = row & 1023;
  const float* ip = xin + (size_t)row * DD;
  const float* per = pe + (size_t)i * DD;
  float v[3]; float s = 0.f, sq = 0.f;
  #pragma unroll
  for (int j = 0; j < 3; ++j){
    int d = j * 256 + tid;
    float x = ip[d] + per[d];
    v[j] = x; s += x; sq += x * x;
  }
  s = wave_sum(s); sq = wave_sum(sq);
  int wv = tid >> 6;
  if ((tid & 63) == 0){ ss[wv] = s; sqq[wv] = sq; }
  __syncthreads();
  s  = ss[0] + ss[1] + ss[2] + ss[3];
  sq = sqq[0] + sqq[1] + sqq[2] + sqq[3];
  float mean = s * (1.f / DD);
  float var  = sq * (1.f / DD) - mean * mean;
  float r = rsqrtf(var + 1e-5f);
  #pragma unroll
  for (int j = 0; j < 3; ++j){
    int d = j * 256 + tid;
    float xn = (v[j] - mean) * r;
    o1[(size_t)row * DD + d] = (h16)(xn * g1[d] + b1[d]);
    o2[(size_t)row * DD + d] = (h16)(xn * g2[d] + b2[d]);
  }
}

// ------- GAT layernorm: h16 state + f32 ctx add -> h16 (in-place safe) ------
__global__ __launch_bounds__(256) void k_lnH(const h16* __restrict__ in,
    const float* __restrict__ ctx, const float* __restrict__ g,
    const float* __restrict__ be, h16* __restrict__ out){
  __shared__ float ss[4], sqq[4];
  int row = blockIdx.x, tid = threadIdx.x;
  const h16* ip = in + (size_t)row * DD;
  int b = row >> 10;
  float v[3]; float s = 0.f, sq = 0.f;
  #pragma unroll
  for (int j = 0; j < 3; ++j){
    int d = j * 256 + tid;
    float x = (float)ip[d] + ctx[b * DD + d];
    v[j] = x; s += x; sq += x * x;
  }
  s = wave_sum(s); sq = wave_sum(sq);
  int w = tid >> 6;
  if ((tid & 63) == 0){ ss[w] = s; sqq[w] = sq; }
  __syncthreads();
  s  = ss[0] + ss[1] + ss[2] + ss[3];
  sq = sqq[0] + sqq[1] + sqq[2] + sqq[3];
  float mean = s * (1.f / DD);
  float var  = sq * (1.f / DD) - mean * mean;
  float r = rsqrtf(var + 1e-5f);
  #pragma unroll
  for (int j = 0; j < 3; ++j){
    int d = j * 256 + tid;
    out[(size_t)row * DD + d] = (h16)((v[j] - mean) * r * g[d] + be[d]);
  }
}

// ---------------- xh = a + b (f16, vectorized) -------------------------------
__global__ __launch_bounds__(256) void k_addh(const h16* __restrict__ a,
    const h16* __restrict__ b, h16* __restrict__ o, int n8){
  int i = blockIdx.x * 256 + threadIdx.x;
  if (i < n8){
    half8v x = ((const half8v*)a)[i];
    half8v y = ((const half8v*)b)[i];
    ((half8v*)o)[i] = x + y;
  }
}

// ======== pipelined GEMM mainloop (BM=128, BN=128, BK=64) ========
#define GEMM_MAINLOOP(Abase, lda, Wbase, ldw, Kdim)                          \
  auto stage = [&](int buf, int kt){                                         \
    _Pragma("unroll")                                                        \
    for (int i = 0; i < 4; ++i){                                             \
      int p = i*256 + tid; int row = p >> 3; int ch = (p & 7) ^ (row & 7);   \
      gload16(Abase + (size_t)(m0+row)*lda + kt + ch*8, &Als[buf][p*8]);     \
    }                                                                        \
    _Pragma("unroll")                                                        \
    for (int i = 0; i < 4; ++i){                                             \
      int p = i*256 + tid; int row = p >> 3; int ch = (p & 7) ^ (row & 7);   \
      gload16(Wbase + (size_t)(n0+row)*ldw + kt + ch*8, &Bls[buf][p*8]);     \
    }                                                                        \
  };                                                                         \
  stage(0, 0);                                                               \
  const int nk = Kdim >> 6;                                                  \
  for (int t = 0; t < nk; ++t){                                              \
    const int cur = t & 1;                                                   \
    if (t + 1 < nk){                                                         \
      stage(cur ^ 1, (t + 1) << 6);                                          \
      asm volatile("s_waitcnt vmcnt(8)" ::: "memory");                       \
    } else {                                                                 \
      asm volatile("s_waitcnt vmcnt(0)" ::: "memory");                       \
    }                                                                        \
    __builtin_amdgcn_s_barrier();                                            \
    __builtin_amdgcn_sched_barrier(0);                                       \
    __builtin_amdgcn_s_setprio(1);                                           \
    _Pragma("unroll")                                                        \
    for (int kk = 0; kk < 2; ++kk){                                          \
      half8v af[4], bf[4];                                                   \
      _Pragma("unroll")                                                      \
      for (int mi = 0; mi < 4; ++mi){                                        \
        int row = wr*64 + mi*16 + lr;                                        \
        int chp = (kk*4 + lg) ^ (row & 7);                                   \
        af[mi] = *(const half8v*)&Als[cur][row*64 + chp*8];                  \
      }                                                                      \
      _Pragma("unroll")                                                      \
      for (int ni = 0; ni < 4; ++ni){                                        \
        int row = wc*64 + ni*16 + lr;                                        \
        int chp = (kk*4 + lg) ^ (row & 7);                                   \
        bf[ni] = *(const half8v*)&Bls[cur][row*64 + chp*8];                  \
      }                                                                      \
      _Pragma("unroll")                                                      \
      for (int mi = 0; mi < 4; ++mi)                                         \
        _Pragma("unroll")                                                    \
        for (int ni = 0; ni < 4; ++ni)                                       \
          acc[mi][ni] = __builtin_amdgcn_mfma_f32_16x16x32_f16(              \
              af[mi], bf[ni], acc[mi][ni], 0, 0, 0);                         \
    }                                                                        \
    __builtin_amdgcn_s_setprio(0);                                           \
    asm volatile("s_waitcnt lgkmcnt(0)" ::: "memory");                       \
    __builtin_amdgcn_sched_barrier(0);                                       \
    __builtin_amdgcn_s_barrier();                                            \
  }

// ---------------- general GEMM (GAT path): fused row-dot --------------------
__global__ __launch_bounds__(256) void k_gemm_h(
    const h16* __restrict__ A, const h16* __restrict__ W,
    int lda, int ldw, int ldc, int K,
    const float* __restrict__ bias,
    h16* __restrict__ outh,
    const float* __restrict__ rdw, float* __restrict__ rdpart)
{
  __shared__ h16 Als[2][128*64];
  __shared__ h16 Bls[2][128*64];
  const int tid = threadIdx.x;
  const int gx = gridDim.x, gy = gridDim.y;
  const int wg = xcd_remap(blockIdx.x + gx * blockIdx.y, gx * gy);
  const int nidx = wg % gx;
  const int n0 = nidx * 128, m0 = (wg / gx) * 128;
  const int lane = tid & 63, wid = tid >> 6;
  const int wr = wid >> 1, wc = wid & 1;
  const int lr = lane & 15, lg = lane >> 4;
  f32x4 acc[4][4] = {};
  GEMM_MAINLOOP(A, lda, W, ldw, K)
  float rd[4][4] = {};
  #pragma unroll
  for (int mi = 0; mi < 4; ++mi){
    #pragma unroll
    for (int ni = 0; ni < 4; ++ni){
      int col = n0 + wc*64 + ni*16 + lr;
      int rowb = m0 + wr*64 + mi*16 + lg*4;
      float cb = bias[col];
      float aw = rdw ? rdw[col] : 0.f;
      #pragma unroll
      for (int r = 0; r < 4; ++r){
        size_t idx = (size_t)(rowb + r) * ldc + col;
        float v = acc[mi][ni][r] + cb;
        outh[idx] = (h16)v;
        if (rdw) rd[mi][r] += v * aw;
      }
    }
  }
  if (rdw){
    #pragma unroll
    for (int mi = 0; mi < 4; ++mi){
      #pragma unroll
      for (int r = 0; r < 4; ++r){
        float p = rd[mi][r];
        #pragma unroll
        for (int o = 1; o < 16; o <<= 1) p += __shfl_xor(p, o);
        if (lr == 0){
          int row = m0 + wr*64 + mi*16 + lg*4 + r;
          rdpart[(size_t)row * 12 + nidx*2 + wc] = p;
        }
      }
    }
  }
}

// ---------------- batched 2-way out-projection GEMM --------------------------
__global__ __launch_bounds__(256) void k_gemmop(
    const h16* __restrict__ A0, const h16* __restrict__ A1,
    const h16* __restrict__ W0, const h16* __restrict__ W1,
    const float* __restrict__ bb0, const float* __restrict__ bb1,
    h16* __restrict__ C0, h16* __restrict__ C1)
{
  __shared__ h16 Als[2][128*64];
  __shared__ h16 Bls[2][128*64];
  const int tid = threadIdx.x;
  const int gx = gridDim.x, gy = gridDim.y;   // 6, 64
  const int nwg = gx * gy * 2;
  const int wg = xcd_remap(blockIdx.x + gx*(blockIdx.y + gy*blockIdx.z), nwg);
  const int n0 = (wg % gx) * 128;
  const int m0 = ((wg / gx) % gy) * 128;
  const int bz = wg / (gx * gy);
  const h16* A = bz ? A1 : A0;
  const h16* W = bz ? W1 : W0;
  const float* bias = bz ? bb1 : bb0;
  h16* C = bz ? C1 : C0;
  const int lane = tid & 63, wid = tid >> 6;
  const int wr = wid >> 1, wc = wid & 1;
  const int lr = lane & 15, lg = lane >> 4;
  f32x4 acc[4][4] = {};
  GEMM_MAINLOOP(A, DD, W, DD, DD)
  #pragma unroll
  for (int mi = 0; mi < 4; ++mi){
    #pragma unroll
    for (int ni = 0; ni < 4; ++ni){
      int col = n0 + wc*64 + ni*16 + lr;
      int rowb = m0 + wr*64 + mi*16 + lg*4;
      float cb = bias[col];
      #pragma unroll
      for (int r = 0; r < 4; ++r)
        C[(size_t)(rowb + r) * DD + col] = (h16)(acc[mi][ni][r] + cb);
    }
  }
}

// ------ conv2 as overlapping-window GEMM over padded X (no im2col) ----------
__global__ __launch_bounds__(256) void k_conv2g(
    const h16* __restrict__ X, const h16* __restrict__ W,
    const float* __restrict__ sc, const float* __restrict__ off,
    h16* __restrict__ out)
{
  __shared__ h16 Als[2][128*64];
  __shared__ h16 Bls[2][128*64];
  const int tid = threadIdx.x;
  const int gx = gridDim.x, gy = gridDim.y;   // 6, 128
  const int wg = xcd_remap(blockIdx.x + gx * blockIdx.y, gx * gy);
  const int n0 = (wg % gx) * 128, m0 = (wg / gx) * 128;
  const int lane = tid & 63, wid = tid >> 6;
  const int wr = wid >> 1, wc = wid & 1;
  const int lr = lane & 15, lg = lane >> 4;
  f32x4 acc[4][4] = {};
  auto stage = [&](int buf, int kt){
    #pragma unroll
    for (int i = 0; i < 4; ++i){
      int p = i*256 + tid; int row = p >> 3; int ch = (p & 7) ^ (row & 7);
      int rm = m0 + row, b = rm >> 11, t = rm & 2047;
      gload16(X + (size_t)b*XROW + (size_t)t*128 + kt + ch*8, &Als[buf][p*8]);
    }
    #pragma unroll
    for (int i = 0; i < 4; ++i){
      int p = i*256 + tid; int row = p >> 3; int ch = (p & 7) ^ (row & 7);
      gload16(W + (size_t)(n0+row)*384 + kt + ch*8, &Bls[buf][p*8]);
    }
  };
  stage(0, 0);
  const int nk = 6;  // K=384
  for (int t = 0; t < nk; ++t){
    const int cur = t & 1;
    if (t + 1 < nk){
      stage(cur ^ 1, (t + 1) << 6);
      asm volatile("s_waitcnt vmcnt(8)" ::: "memory");
    } else {
      asm volatile("s_waitcnt vmcnt(0)" ::: "memory");
    }
    __builtin_amdgcn_s_barrier();
    __builtin_amdgcn_sched_barrier(0);
    __builtin_amdgcn_s_setprio(1);
    #pragma unroll
    for (int kk = 0; kk < 2; ++kk){
      half8v af[4], bf[4];
      #pragma unroll
      for (int mi = 0; mi < 4; ++mi){
        int row = wr*64 + mi*16 + lr;
        int chp = (kk*4 + lg) ^ (row & 7);
        af[mi] = *(const half8v*)&Als[cur][row*64 + chp*8];
      }
      #pragma unroll
      for (int ni = 0; ni < 4; ++ni){
        int row = wc*64 + ni*16 + lr;
        int chp = (kk*4 + lg) ^ (row & 7);
        bf[ni] = *(const half8v*)&Bls[cur][row*64 + chp*8];
      }
      #pragma unroll
      for (int mi = 0; mi < 4; ++mi)
        #pragma unroll
        for (int ni = 0; ni < 4; ++ni)
          acc[mi][ni] = __builtin_amdgcn_mfma_f32_16x16x32_f16(
              af[mi], bf[ni], acc[mi][ni], 0, 0, 0);
    }
    __builtin_amdgcn_s_setprio(0);
    asm volatile("s_waitcnt lgkmcnt(0)" ::: "memory");
    __builtin_amdgcn_sched_barrier(0);
    __builtin_amdgcn_s_barrier();
  }
  #pragma unroll
  for (int mi = 0; mi < 4; ++mi){
    #pragma unroll
    for (int ni = 0; ni < 4; ++ni){
      int col = n0 + wc*64 + ni*16 + lr;
      int rowb = m0 + wr*64 + mi*16 + lg*4;
      #pragma unroll
      for (int r = 0; r < 4; ++r){
        int rm = rowb + r, b = rm >> 11, t = rm & 2047;
        if (t < TLEN){
          float v = acc[mi][ni][r] * sc[col] + off[col];
          out[((size_t)b*TLEN + t)*DD + col] = (h16)gelu_f(v);
        }
      }
    }
  }
}

// ---------------- batched 6-way QKV projection GEMM --------------------------
__global__ __launch_bounds__(256) void k_gemm6(
    const h16* __restrict__ Lall, const h16* __restrict__ w6,
    const float* __restrict__ b1, const float* __restrict__ b2,
    h16* __restrict__ qkv6)
{
  __shared__ h16 Als[2][128*64];
  __shared__ h16 Bls[2][128*64];
  const int tid = threadIdx.x;
  const int gx = gridDim.x, gy = gridDim.y;   // 6, 64
  const int nwg = gx * gy * 6;
  const int wg = xcd_remap(blockIdx.x + gx*(blockIdx.y + gy*blockIdx.z), nwg);
  const int n0 = (wg % gx) * 128;
  const int m0 = ((wg / gx) % gy) * 128;
  const int bz = wg / (gx * gy);
  const int aidx = (1468 >> (2*bz)) & 3;      // {0,3,3,2,1,1}
  const h16* A = Lall + (size_t)aidx * SLOT;
  const h16* W = w6 + (size_t)bz * 589824;
  const float* bias = (bz < 3 ? b1 + bz*DD : b2 + (bz-3)*DD);
  h16* C = qkv6 + (size_t)bz * SLOT;
  const int lane = tid & 63, wid = tid >> 6;
  const int wr = wid >> 1, wc = wid & 1;
  const int lr = lane & 15, lg = lane >> 4;
  f32x4 acc[4][4] = {};
  GEMM_MAINLOOP(A, DD, W, DD, DD)
  #pragma unroll
  for (int mi = 0; mi < 4; ++mi){
    #pragma unroll
    for (int ni = 0; ni < 4; ++ni){
      int col = n0 + wc*64 + ni*16 + lr;
      int rowb = m0 + wr*64 + mi*16 + lg*4;
      float cb = bias[col];
      #pragma unroll
      for (int r = 0; r < 4; ++r)
        C[(size_t)(rowb + r) * DD + col] = (h16)(acc[mi][ni][r] + cb);
    }
  }
}

// ------- merged V transpose: z = which*32 + bh ------------------------------
__global__ __launch_bounds__(256) void k_trV(const h16* __restrict__ V0,
    const h16* __restrict__ V1, h16* __restrict__ VT0, h16* __restrict__ VT1){
  __shared__ h16 tile[64*64];
  const int zz = blockIdx.z;
  const int which = zz >> 5, bh = zz & 31;
  const int b = bh >> 2, h = bh & 3;
  const h16* Vh = which ? V1 : V0;
  h16* VT = which ? VT1 : VT0;
  const int q0 = blockIdx.x * 64, d0 = blockIdx.y * 64;
  const int t = threadIdx.x;
  {
    int qq = t >> 2, ds = (t & 3) * 16;
    const h16* src = Vh + ((size_t)b*NSEQ + q0 + qq)*DD + h*HDIM + d0 + ds;
    half8v v0 = *(const half8v*)src;
    half8v v1 = *(const half8v*)(src + 8);
    int c0 = (ds >> 3) ^ (qq & 7), c1 = ((ds >> 3) + 1) ^ (qq & 7);
    *(half8v*)&tile[qq*64 + c0*8] = v0;
    *(half8v*)&tile[qq*64 + c1*8] = v1;
  }
  __syncthreads();
  {
    int dd = t >> 2, qs = (t & 3) * 16;
    half8v o0, o1;
    #pragma unroll
    for (int j = 0; j < 8; ++j){
      int q = qs + j, q2 = qs + 8 + j;
      o0[j] = tile[q*64  + (((dd>>3) ^ (q&7))*8)  + (dd & 7)];
      o1[j] = tile[q2*64 + (((dd>>3) ^ (q2&7))*8) + (dd & 7)];
    }
    h16* dst = VT + (size_t)bh*HDIM*NSEQ + (size_t)(d0+dd)*NSEQ + q0 + qs;
    *(half8v*)dst = o0;
    *(half8v*)(dst + 8) = o1;
  }
}

// ------- merged flash attention: prescaled-Q exp2, ones-column l -------------
__global__ __launch_bounds__(256, 3) void k_flash(
    const h16* __restrict__ Q0, const h16* __restrict__ K0,
    const h16* __restrict__ T0, h16* __restrict__ O0,
    const h16* __restrict__ Q1, const h16* __restrict__ K1,
    const h16* __restrict__ T1, h16* __restrict__ O1){
  __shared__ h16 Ks[2][32*192];
  __shared__ h16 Vs[2][192*32];
  __shared__ h16 Ps[4][16*32];
  const int tid = threadIdx.x;
  const int bh = blockIdx.x, qt = blockIdx.y, which = blockIdx.z;
  const int b = bh >> 2, h = bh & 3;
  const int q0 = qt * 64;
  const h16* Qp = which ? Q1 : Q0;
  const h16* Kp = which ? K1 : K0;
  const h16* VTp = which ? T1 : T0;
  h16* Op = which ? O1 : O0;
  const h16* Qg = Qp + (size_t)b*NSEQ*DD + h*HDIM;
  const h16* Kg = Kp + (size_t)b*NSEQ*DD + h*HDIM;
  const h16* Vg = VTp + (size_t)bh*HDIM*NSEQ;
  const int lane = tid & 63, wid = tid >> 6;
  const int lr = lane & 15, lg = lane >> 4;
  const float SC2 = 0.07216878364870322f * 1.4426950408889634f;  // /sqrt(192)*log2e
  half8v qf[6];
  {
    int qrow = q0 + wid*16 + lr;
    const h16 qs2 = (h16)SC2;
    #pragma unroll
    for (int ks = 0; ks < 6; ++ks){
      half8v qv = *(const half8v*)(Qg + (size_t)qrow*DD + ks*32 + lg*8);
      #pragma unroll
      for (int j = 0; j < 8; ++j) qv[j] = qv[j] * qs2;   // pre-scale: S in log2 units
      qf[ks] = qv;
    }
  }
  auto stageK = [&](int buf, int k0){
    #pragma unroll
    for (int i = 0; i < 3; ++i){
      int p = i*256 + tid;
      int row = p / 24, chp = p % 24;
      int ch = chp ^ (row & 7);
      gload16(Kg + (size_t)(k0+row)*DD + ch*8, &Ks[buf][p*8]);
    }
  };
  auto stageV = [&](int buf, int k0){
    #pragma unroll
    for (int i = 0; i < 3; ++i){
      int p = i*256 + tid;
      int row = p >> 2, chp = p & 3;
      int ch = chp ^ ((row >> 1) & 3);
      gload16(Vg + (size_t)row*NSEQ + k0 + ch*8, &Vs[buf][p*8]);
    }
  };
  stageK(0, 0); stageV(0, 0);
  f32x4 oacc[12] = {};
  f32x4 osum = {0.f, 0.f, 0.f, 0.f};   // ones-column accumulator = per-row l
  float m2[4] = {-1e30f, -1e30f, -1e30f, -1e30f};  // running max, log2 domain
  half8v vone;
  #pragma unroll
  for (int j = 0; j < 8; ++j) vone[j] = (h16)1.f;
  for (int kt = 0; kt < 32; ++kt){
    const int cur = kt & 1;
    if (kt + 1 < 32){
      stageK(cur^1, (kt+1)*32); stageV(cur^1, (kt+1)*32);
      asm volatile("s_waitcnt vmcnt(6)" ::: "memory");
    } else {
      asm volatile("s_waitcnt vmcnt(0)" ::: "memory");
    }
    __builtin_amdgcn_s_barrier();
    __builtin_amdgcn_sched_barrier(0);
    f32x4 sacc[2] = {};
    __builtin_amdgcn_s_setprio(1);
    #pragma unroll
    for (int ks = 0; ks < 6; ++ks){
      #pragma unroll
      for (int t = 0; t < 2; ++t){
        int krow = t*16 + lr;
        int ch = (ks*4 + lg) ^ (krow & 7);
        half8v kf = *(const half8v*)&Ks[cur][krow*192 + ch*8];
        sacc[t] = __builtin_amdgcn_mfma_f32_16x16x32_f16(qf[ks], kf, sacc[t], 0, 0, 0);
      }
    }
    __builtin_amdgcn_s_setprio(0);
    // ballot-gated defer-max (sacc already in log2 units)
    float lmaxr[4];
    #pragma unroll
    for (int r = 0; r < 4; ++r) lmaxr[r] = fmaxf(sacc[0][r], sacc[1][r]);
    bool flag = false;
    #pragma unroll
    for (int r = 0; r < 4; ++r) flag |= (lmaxr[r] > m2[r] + 14.f);
    if (__ballot(flag)){
      float c[4];
      #pragma unroll
      for (int r = 0; r < 4; ++r){
        float mt = lmaxr[r];
        #pragma unroll
        for (int off = 1; off < 16; off <<= 1) mt = fmaxf(mt, __shfl_xor(mt, off));
        if (mt > m2[r]){ c[r] = exp2f(m2[r] - mt); m2[r] = mt; }
        else c[r] = 1.f;
      }
      #pragma unroll
      for (int dt = 0; dt < 12; ++dt){
        f32x4 o = oacc[dt];
        o[0] *= c[0]; o[1] *= c[1]; o[2] *= c[2]; o[3] *= c[3];
        oacc[dt] = o;
      }
      osum[0] *= c[0]; osum[1] *= c[1]; osum[2] *= c[2]; osum[3] *= c[3];
    }
    #pragma unroll
    for (int t = 0; t < 2; ++t){
      #pragma unroll
      for (int r = 0; r < 4; ++r){
        float p = exp2f(sacc[t][r] - m2[r]);
        int q = lg*4 + r, key = t*16 + lr;
        int ch = (t*2 + (lr>>3)) ^ ((q>>1) & 3);
        Ps[wid][q*32 + ch*8 + (key & 7)] = (h16)p;
      }
    }
    asm volatile("s_waitcnt lgkmcnt(0)" ::: "memory");   // own-wave P writes done
    __builtin_amdgcn_sched_barrier(0);
    {
      int pch = lg ^ ((lr >> 1) & 3);
      half8v pf = *(const half8v*)&Ps[wid][lr*32 + pch*8];
      __builtin_amdgcn_s_setprio(1);
      #pragma unroll
      for (int dt = 0; dt < 12; ++dt){
        int drow = dt*16 + lr;
        int vch = lg ^ ((drow >> 1) & 3);
        half8v vf = *(const half8v*)&Vs[cur][drow*32 + vch*8];
        oacc[dt] = __builtin_amdgcn_mfma_f32_16x16x32_f16(pf, vf, oacc[dt], 0, 0, 0);
      }
      osum = __builtin_amdgcn_mfma_f32_16x16x32_f16(pf, vone, osum, 0, 0, 0);
      __builtin_amdgcn_s_setprio(0);
    }
    asm volatile("s_waitcnt lgkmcnt(0)" ::: "memory");   // LDS reads of cur retired
    __builtin_amdgcn_sched_barrier(0);
    __builtin_amdgcn_s_barrier();                         // safe to overwrite cur
  }
  float inv[4];
  #pragma unroll
  for (int r = 0; r < 4; ++r) inv[r] = 1.0f / osum[r];
  h16* Og = Op + (size_t)b*NSEQ*DD + h*HDIM;
  #pragma unroll
  for (int dt = 0; dt < 12; ++dt){
    #pragma unroll
    for (int r = 0; r < 4; ++r){
      int q = q0 + wid*16 + lg*4 + r;
      Og[(size_t)q*DD + dt*16 + lr] = (h16)(oacc[dt][r] * inv[r]);
    }
  }
}

// -------- fused GAT softmax + ctx stage1: alpha computed per-block ----------
// grid (3, 8, 16): block computes softmax over rowdot partials (batch b),
// keeps its 64 alphas in LDS, then accumulates its 64-j partial of ctx.
__global__ __launch_bounds__(256) void k_ctxs(const float* __restrict__ rdpart,
    const h16* __restrict__ h, float* __restrict__ part){
  __shared__ float red[4];
  __shared__ float al[64];
  const int tid = threadIdx.x;
  const int b = blockIdx.y, pc = blockIdx.z;
  float v[4]; float mx = -1e30f;
  #pragma unroll
  for (int j = 0; j < 4; ++j){
    int i = j * 256 + tid;
    const float* p = rdpart + (size_t)(b * NSEQ + i) * 12;
    float s = 0.f;
    #pragma unroll
    for (int k = 0; k < 12; ++k) s += p[k];
    v[j] = s; mx = fmaxf(mx, s);
  }
  mx = wave_max(mx);
  if ((tid & 63) == 0) red[tid >> 6] = mx;
  __syncthreads();
  mx = fmaxf(fmaxf(red[0], red[1]), fmaxf(red[2], red[3]));
  __syncthreads();
  float s = 0.f;
  #pragma unroll
  for (int j = 0; j < 4; ++j){ v[j] = __expf(v[j] - mx); s += v[j]; }
  s = wave_sum(s);
  if ((tid & 63) == 0) red[tid >> 6] = s;
  __syncthreads();
  s = red[0] + red[1] + red[2] + red[3];
  float inv = 1.0f / s;
  #pragma unroll
  for (int j = 0; j < 4; ++j){
    int i = j * 256 + tid;
    int rel = i - pc * 64;
    if (rel >= 0 && rel < 64) al[rel] = v[j] * inv;
  }
  __syncthreads();
  int d = blockIdx.x * 256 + tid;     // 3*256 = 768, always < DD
  float acc = 0.f;
  const h16* hp = h + ((size_t)b * NSEQ + pc * 64) * DD + d;
  #pragma unroll 4
  for (int j = 0; j < 64; ++j) acc += al[j] * (float)hp[(size_t)j * DD];
  part[(size_t)(b * 16 + pc) * DD + d] = acc;
}

__global__ __launch_bounds__(256) void k_ctx2(const float* __restrict__ part,
    float scale, float* __restrict__ ctx){
  int d = blockIdx.x * 256 + threadIdx.x;
  int b = blockIdx.y;
  if (d >= DD) return;
  float acc = 0.f;
  #pragma unroll
  for (int p = 0; p < 16; ++p) acc += part[(size_t)(b * 16 + p) * DD + d];
  ctx[b * DD + d] = acc * scale;
}

__global__ __launch_bounds__(256) void k_pool1(const h16* __restrict__ x,
    float* __restrict__ part){
  int d = blockIdx.x * 256 + threadIdx.x;
  int b = blockIdx.y, pc = blockIdx.z;
  if (d >= DD) return;
  float acc = 0.f;
  const h16* xp = x + ((size_t)b * NSEQ + pc * 64) * DD + d;
  #pragma unroll 4
  for (int j = 0; j < 64; ++j) acc += (float)xp[(size_t)j * DD];
  part[(size_t)(b * 16 + pc) * DD + d] = acc;
}

__global__ __launch_bounds__(128) void k_clf(const float* __restrict__ pooled,
    const float* __restrict__ w1, const float* __restrict__ b1,
    const float* __restrict__ w2, const float* __restrict__ b2,
    float* __restrict__ out){
  __shared__ float pl[DD];
  __shared__ float h1[128];
  int b = blockIdx.x, tid = threadIdx.x;
  #pragma unroll
  for (int j = 0; j < 6; ++j) pl[j * 128 + tid] = pooled[b * DD + j * 128 + tid];
  __syncthreads();
  float acc = b1[tid];
  const float* wp = w1 + (size_t)tid * DD;
  for (int d = 0; d < DD; ++d) acc += pl[d] * wp[d];
  h1[tid] = gelu_f(acc);
  __syncthreads();
  if (tid < 2){
    float o = b2[tid];
    const float* w2p = w2 + tid * 128;
    for (int c = 0; c < 128; ++c) o += h1[c] * w2p[c];
    out[b * 2 + tid] = o;
  }
}

// =========================== launcher ===========================
extern "C" void kernel_launch(void* const* d_in, const int* in_sizes, int n_in,
                              void* d_out, int out_size, void* d_ws, size_t ws_size,
                              hipStream_t stream){
  (void)in_sizes; (void)n_in; (void)out_size;
  const float* w2v      = (const float*)d_in[0];
  const float* cqcc     = (const float*)d_in[1];
  const float* conv1_w  = (const float*)d_in[2];
  const float* conv1_b  = (const float*)d_in[3];
  const float* bn1_g    = (const float*)d_in[4];
  const float* bn1_b    = (const float*)d_in[5];
  const float* bn1_m    = (const float*)d_in[6];
  const float* bn1_v    = (const float*)d_in[7];
  const float* conv2_w  = (const float*)d_in[8];
  const float* conv2_b  = (const float*)d_in[9];
  const float* bn2_g    = (const float*)d_in[10];
  const float* bn2_b    = (const float*)d_in[11];
  const float* bn2_m    = (const float*)d_in[12];
  const float* bn2_v    = (const float*)d_in[13];
  const float* pos_embed= (const float*)d_in[14];
  const float* lnq_g    = (const float*)d_in[15];
  const float* lnq_b    = (const float*)d_in[16];
  const float* lnkv_g   = (const float*)d_in[17];
  const float* lnkv_b   = (const float*)d_in[18];
  const float* a1_in_w  = (const float*)d_in[19];
  const float* a1_in_b  = (const float*)d_in[20];
  const float* a1_out_w = (const float*)d_in[21];
  const float* a1_out_b = (const float*)d_in[22];
  const float* a2_in_w  = (const float*)d_in[23];
  const float* a2_in_b  = (const float*)d_in[24];
  const float* a2_out_w = (const float*)d_in[25];
  const float* a2_out_b = (const float*)d_in[26];
  const float* gat_fc_w = (const float*)d_in[27];
  const float* gat_fc_b = (const float*)d_in[28];
  const float* gat_a_w  = (const float*)d_in[29];
  // d_in[30] gat_a_b: cancels in softmax over j — unused.
  const float* gln_g    = (const float*)d_in[31];
  const float* gln_b    = (const float*)d_in[32];
  const float* clf_w1   = (const float*)d_in[33];
  const float* clf_b1   = (const float*)d_in[34];
  const float* clf_w2   = (const float*)d_in[35];
  const float* clf_b2   = (const float*)d_in[36];

  char* wsp = (char*)d_ws;
  auto F = [&](size_t bytes){ char* p = wsp; wsp += (bytes + 255) & ~(size_t)255; return p; };
  h16* xh      = (h16*)F(12582912);       // GAT running state (f16)
  h16* Lall    = (h16*)F(4*12582912);     // LN slots 0..3; also conv X buffer
  h16* qkv6    = (h16*)F(6*12582912);     // Q1 K1 V1 Q2 K2 V2; also x2h f16
  h16* VT      = (h16*)F(12582912);
  h16* VT2     = (h16*)F(12582912);
  h16* o1h     = (h16*)F(12582912);
  h16* o2h     = (h16*)F(12582912);
  h16* w6      = (h16*)F(2*3538944);      // Wqkv1 | Wqkv2
  h16* w_a1out = (h16*)F(1179648);
  h16* w_a2out = (h16*)F(1179648);
  h16* w_gat   = (h16*)F(3538944);
  h16* w_c2    = (h16*)F(589824);
  float* scb   = (float*)F(3072);
  float* offb  = (float*)F(3072);
  float* ctxb  = (float*)F(24576);
  float* pooled= (float*)F(24576);
  float* partb = (float*)F(393216);       // rowdot 8192x12 f32 / pool partials
  float* partc = (float*)F(393216);       // ctx partials 8x16x768 f32
  if ((size_t)(wsp - (char*)d_ws) > ws_size) return;

  h16* X   = Lall;                        // padded conv buffer [8][2002][128]
  h16* x2h = qkv6;                        // conv2 out f16 (24.6 MB, slots 0-1)
  h16* hh  = qkv6;                        // GAT h (slot0, dead after outproj)

  const int NR = BBATCH * NSEQ;           // 8192

  // --- merged weight casts + conv2 permute-cast + bn prep ---
  {
    CastArgs ca;
    ca.s[0]=a1_in_w;  ca.d[0]=w6;            int n0=1769472;
    ca.s[1]=a2_in_w;  ca.d[1]=w6+1769472;    int n1=1769472;
    ca.s[2]=a1_out_w; ca.d[2]=w_a1out;       int n2=589824;
    ca.s[3]=a2_out_w; ca.d[3]=w_a2out;       int n3=589824;
    ca.s[4]=gat_fc_w; ca.d[4]=w_gat;         int n4=1769472;
    ca.cum[0]=0; ca.cum[1]=n0; ca.cum[2]=n0+n1; ca.cum[3]=n0+n1+n2;
    ca.cum[4]=n0+n1+n2+n3; ca.cum[5]=n0+n1+n2+n3+n4;
    int total = ca.cum[5];
    k_cast5<<<(total+255)/256, 256, 0, stream>>>(ca, total);
  }
  k_castc2<<<(294912+255)/256, 256, 0, stream>>>(conv2_w, w_c2);
  k_bnprep<<<3, 256, 0, stream>>>(conv2_b, bn2_g, bn2_b, bn2_m, bn2_v, scb, offb);

  // --- front-end convs (no im2col) ---
  k_conv1t<<<dim3(8, 4, BBATCH), 256, 0, stream>>>(cqcc, conv1_w, conv1_b,
      bn1_g, bn1_b, bn1_m, bn1_v, X);
  k_conv2g<<<dim3(6, 128), 256, 0, stream>>>(X, w_c2, scb, offb, x2h);

  // --- fused interp/addpos + dual LN (slots 0..3) ---
  k_interp_ln<<<NR, 256, 0, stream>>>(x2h, pos_embed,
      lnq_g, lnq_b, Lall, lnkv_g, lnkv_b, Lall + SLOT);
  k_addpos_ln<<<NR, 256, 0, stream>>>(w2v, pos_embed,
      lnq_g, lnq_b, Lall + 2*SLOT, lnkv_g, lnkv_b, Lall + 3*SLOT);

  // --- all six QKV projections in one dispatch ---
  k_gemm6<<<dim3(6, 64, 6), 256, 0, stream>>>(Lall, w6, a1_in_b, a2_in_b, qkv6);

  // ================= both MHAs, merged =================
  k_trV<<<dim3(16, 3, 64), 256, 0, stream>>>(qkv6 + 2*(size_t)SLOT,
      qkv6 + 5*(size_t)SLOT, VT, VT2);
  k_flash<<<dim3(32, 16, 2), 256, 0, stream>>>(
      qkv6, qkv6 + (size_t)SLOT, VT, qkv6,                        // MHA1: O1 -> slot0
      qkv6 + 3*(size_t)SLOT, qkv6 + 4*(size_t)SLOT, VT2,
      qkv6 + 3*(size_t)SLOT);                                     // MHA2: O2 -> slot3
  k_gemmop<<<dim3(6, 64, 2), 256, 0, stream>>>(
      qkv6, qkv6 + 3*(size_t)SLOT, w_a1out, w_a2out,
      a1_out_b, a2_out_b, o1h, o2h);
  k_addh<<<(NR*DD/8 + 255)/256, 256, 0, stream>>>(o1h, o2h, xh, NR*DD/8);

  // ================= GAT x3 (rowdot fused; softmax fused into ctx) ==========
  for (int l = 0; l < 3; ++l){
    k_gemm_h<<<dim3(6, 64), 256, 0, stream>>>(xh, w_gat + (size_t)l*589824,
        DD, DD, DD, DD, gat_fc_b + l*DD, hh, gat_a_w + l*2*DD + DD, partb);
    k_ctxs<<<dim3(3, BBATCH, 16), 256, 0, stream>>>(partb, hh, partc);
    k_ctx2<<<dim3(3, BBATCH), 256, 0, stream>>>(partc, 1.0f, ctxb);
    k_lnH<<<NR, 256, 0, stream>>>(xh, ctxb, gln_g + l*DD, gln_b + l*DD, xh);
  }

  k_pool1<<<dim3(3, BBATCH, 16), 256, 0, stream>>>(xh, partb);
  k_ctx2<<<dim3(3, BBATCH), 256, 0, stream>>>(partb, 1.0f/NSEQ, pooled);
  k_clf<<<BBATCH, 128, 0, stream>>>(pooled, clf_w1, clf_b1, clf_w2, clf_b2,
                                    (float*)d_out);
}

// Round 18
// 519.458 us; speedup vs baseline: 1.0468x; 1.0118x over previous
//
#include <hip/hip_runtime.h>
#include <math.h>

#define DD 768
#define NH 4
#define HDIM 192
#define BBATCH 8
#define NSEQ 1024
#define TLEN 2000
#define SLOT 6291456   // 8192*768 elements
#define XROW 256256    // per-batch rows in padded conv buffer: 2002*128

typedef _Float16 h16;
typedef _Float16 half8v __attribute__((ext_vector_type(8)));
typedef _Float16 half4v __attribute__((ext_vector_type(4)));
typedef float f32x4 __attribute__((ext_vector_type(4)));

__device__ __forceinline__ float gelu_f(float x){
  return 0.5f * x * (1.0f + erff(x * 0.70710678118654752440f));
}
__device__ __forceinline__ float wave_sum(float v){
  #pragma unroll
  for (int off = 32; off; off >>= 1) v += __shfl_xor(v, off);
  return v;
}
__device__ __forceinline__ float wave_max(float v){
  #pragma unroll
  for (int off = 32; off; off >>= 1) v = fmaxf(v, __shfl_xor(v, off));
  return v;
}
__device__ __forceinline__ void gload16(const h16* g, h16* l){
  __builtin_amdgcn_global_load_lds(
      (const __attribute__((address_space(1))) void*)g,
      (__attribute__((address_space(3))) void*)l, 16, 0, 0);
}
// m204 bijective XCD remap
__device__ __forceinline__ int xcd_remap(int orig, int nwg){
  int q = nwg >> 3, r = nwg & 7;
  int xcd = orig & 7, idx = orig >> 3;
  return (xcd < r ? xcd * (q + 1) : r * (q + 1) + (xcd - r) * q) + idx;
}

// ---------------- merged f32 -> f16 cast (5 segments, 1 dispatch) ------------
struct CastArgs {
  const float* s[5];
  h16* d[5];
  int cum[6];
};
__global__ __launch_bounds__(256) void k_cast5(CastArgs a, int total){
  int i = blockIdx.x * 256 + threadIdx.x;
  if (i >= total) return;
  int seg = 0;
  #pragma unroll
  for (int t = 1; t < 5; ++t) seg += (i >= a.cum[t]);
  int off = i - a.cum[seg];
  a.d[seg][off] = (h16)a.s[seg][off];
}

// ------ conv2 weight cast + permute: (OC,IC,KH) ic-major -> kh-major --------
__global__ __launch_bounds__(256) void k_castc2(const float* __restrict__ s,
    h16* __restrict__ d){
  int i = blockIdx.x * 256 + threadIdx.x;
  if (i >= 294912) return;
  int oc = i / 384, rem = i % 384;
  int ic = rem / 3, kh = rem % 3;
  d[oc * 384 + kh * 128 + ic] = (h16)s[i];
}

// ------ conv1 (20->128, k=3) + bn + gelu -> padded f16 X[b][2002][128] -------
__global__ __launch_bounds__(256) void k_conv1t(const float* __restrict__ cqcc,
    const float* __restrict__ w, const float* __restrict__ bias,
    const float* __restrict__ g, const float* __restrict__ be,
    const float* __restrict__ mm, const float* __restrict__ vv,
    h16* __restrict__ X){
  __shared__ float xs[20][258];
  __shared__ float wsm[32*60];
  const int t0 = blockIdx.x * 256;
  const int ocg = blockIdx.y, b = blockIdx.z;
  const int tid = threadIdx.x;
  for (int idx = tid; idx < 20*258; idx += 256){
    int ic = idx / 258, tt = idx % 258;
    int t = t0 + tt - 1;
    xs[ic][tt] = (t >= 0 && t < TLEN) ? cqcc[((size_t)b*20 + ic)*TLEN + t] : 0.f;
  }
  for (int idx = tid; idx < 32*60; idx += 256)
    wsm[idx] = w[ocg*32*60 + idx];
  __syncthreads();
  int t = t0 + tid;
  if (t >= TLEN) return;
  float acc[32] = {};
  for (int ic = 0; ic < 20; ++ic){
    float x0 = xs[ic][tid], x1v = xs[ic][tid+1], x2v = xs[ic][tid+2];
    #pragma unroll
    for (int oc = 0; oc < 32; ++oc){
      const float* wp = &wsm[(oc*20 + ic)*3];
      acc[oc] += wp[0]*x0 + wp[1]*x1v + wp[2]*x2v;
    }
  }
  h16* dst = X + (size_t)b*XROW + (size_t)(t+1)*128 + ocg*32;
  #pragma unroll 4
  for (int oc = 0; oc < 32; ++oc){
    int c = ocg*32 + oc;
    float s = rsqrtf(vv[c] + 1e-5f) * g[c];
    float val = (acc[oc] + bias[c] - mm[c]) * s + be[c];
    dst[oc] = (h16)gelu_f(val);
  }
  if (t == 0){
    h16* z = X + (size_t)b*XROW + ocg*32;
    #pragma unroll
    for (int oc = 0; oc < 32; ++oc) z[oc] = (h16)0.f;
  }
  if (t == TLEN-1){
    h16* z = X + (size_t)b*XROW + (size_t)2001*128 + ocg*32;
    #pragma unroll
    for (int oc = 0; oc < 32; ++oc) z[oc] = (h16)0.f;
  }
}

// ---------------- BN epilogue constants for conv2 ----------------
__global__ void k_bnprep(const float* __restrict__ cb, const float* __restrict__ g,
    const float* __restrict__ be, const float* __restrict__ m,
    const float* __restrict__ v, float* __restrict__ sc, float* __restrict__ off){
  int i = blockIdx.x * 256 + threadIdx.x;
  if (i >= DD) return;
  float s = g[i] * rsqrtf(v[i] + 1e-5f);
  sc[i] = s;
  off[i] = (cb[i] - m[i]) * s + be[i];
}

// ------- fused interp(2000->1024)+pos + dual LN (h16 input) -----------------
__global__ __launch_bounds__(256) void k_interp_ln(const h16* __restrict__ x2,
    const float* __restrict__ pe,
    const float* __restrict__ g1, const float* __restrict__ b1, h16* __restrict__ o1,
    const float* __restrict__ g2, const float* __restrict__ b2, h16* __restrict__ o2){
  __shared__ float ss[4], sqq[4];
  int row = blockIdx.x, tid = threadIdx.x;
  int b = row >> 10, i = row & 1023;
  float p = (i + 0.5f) * ((float)TLEN / (float)NSEQ) - 0.5f;
  p = fminf(fmaxf(p, 0.f), (float)(TLEN - 1));
  int lo = (int)floorf(p);
  int hi = min(lo + 1, TLEN - 1);
  float w = p - (float)lo;
  const h16* blo = x2 + ((size_t)b * TLEN + lo) * DD;
  const h16* bhi = x2 + ((size_t)b * TLEN + hi) * DD;
  const float* per = pe + (size_t)i * DD;
  float v[3]; float s = 0.f, sq = 0.f;
  #pragma unroll
  for (int j = 0; j < 3; ++j){
    int d = j * 256 + tid;
    float x = (float)blo[d] * (1.f - w) + (float)bhi[d] * w + per[d];
    v[j] = x; s += x; sq += x * x;
  }
  s = wave_sum(s); sq = wave_sum(sq);
  int wv = tid >> 6;
  if ((tid & 63) == 0){ ss[wv] = s; sqq[wv] = sq; }
  __syncthreads();
  s  = ss[0] + ss[1] + ss[2] + ss[3];
  sq = sqq[0] + sqq[1] + sqq[2] + sqq[3];
  float mean = s * (1.f / DD);
  float var  = sq * (1.f / DD) - mean * mean;
  float r = rsqrtf(var + 1e-5f);
  #pragma unroll
  for (int j = 0; j < 3; ++j){
    int d = j * 256 + tid;
    float xn = (v[j] - mean) * r;
    o1[(size_t)row * DD + d] = (h16)(xn * g1[d] + b1[d]);
    o2[(size_t)row * DD + d] = (h16)(xn * g2[d] + b2[d]);
  }
}

// ------- fused w2v+pos + dual LN --------------------------------------------
__global__ __launch_bounds__(256) void k_addpos_ln(const float* __restrict__ xin,
    const float* __restrict__ pe,
    const float* __restrict__ g1, const float* __restrict__ b1, h16* __restrict__ o1,
    const float* __restrict__ g2, const float* __restrict__ b2, h16* __restrict__ o2){
  __shared__ float ss[4], sqq[4];
  int row = blockIdx.x, tid = threadIdx.x;
  int i = row & 1023;
  const float* ip = xin + (size_t)row * DD;
  const float* per = pe + (size_t)i * DD;
  float v[3]; float s = 0.f, sq = 0.f;
  #pragma unroll
  for (int j = 0; j < 3; ++j){
    int d = j * 256 + tid;
    float x = ip[d] + per[d];
    v[j] = x; s += x; sq += x * x;
  }
  s = wave_sum(s); sq = wave_sum(sq);
  int wv = tid >> 6;
  if ((tid & 63) == 0){ ss[wv] = s; sqq[wv] = sq; }
  __syncthreads();
  s  = ss[0] + ss[1] + ss[2] + ss[3];
  sq = sqq[0] + sqq[1] + sqq[2] + sqq[3];
  float mean = s * (1.f / DD);
  float var  = sq * (1.f / DD) - mean * mean;
  float r = rsqrtf(var + 1e-5f);
  #pragma unroll
  for (int j = 0; j < 3; ++j){
    int d = j * 256 + tid;
    float xn = (v[j] - mean) * r;
    o1[(size_t)row * DD + d] = (h16)(xn * g1[d] + b1[d]);
    o2[(size_t)row * DD + d] = (h16)(xn * g2[d] + b2[d]);
  }
}

// ------- GAT layernorm: h16 state + f32 ctx add -> h16 (in-place safe) ------
__global__ __launch_bounds__(256) void k_lnH(const h16* __restrict__ in,
    const float* __restrict__ ctx, const float* __restrict__ g,
    const float* __restrict__ be, h16* __restrict__ out){
  __shared__ float ss[4], sqq[4];
  int row = blockIdx.x, tid = threadIdx.x;
  const h16* ip = in + (size_t)row * DD;
  int b = row >> 10;
  float v[3]; float s = 0.f, sq = 0.f;
  #pragma unroll
  for (int j = 0; j < 3; ++j){
    int d = j * 256 + tid;
    float x = (float)ip[d] + ctx[b * DD + d];
    v[j] = x; s += x; sq += x * x;
  }
  s = wave_sum(s); sq = wave_sum(sq);
  int w = tid >> 6;
  if ((tid & 63) == 0){ ss[w] = s; sqq[w] = sq; }
  __syncthreads();
  s  = ss[0] + ss[1] + ss[2] + ss[3];
  sq = sqq[0] + sqq[1] + sqq[2] + sqq[3];
  float mean = s * (1.f / DD);
  float var  = sq * (1.f / DD) - mean * mean;
  float r = rsqrtf(var + 1e-5f);
  #pragma unroll
  for (int j = 0; j < 3; ++j){
    int d = j * 256 + tid;
    out[(size_t)row * DD + d] = (h16)((v[j] - mean) * r * g[d] + be[d]);
  }
}

// ---------------- xh = a + b (f16, vectorized) -------------------------------
__global__ __launch_bounds__(256) void k_addh(const h16* __restrict__ a,
    const h16* __restrict__ b, h16* __restrict__ o, int n8){
  int i = blockIdx.x * 256 + threadIdx.x;
  if (i < n8){
    half8v x = ((const half8v*)a)[i];
    half8v y = ((const half8v*)b)[i];
    ((half8v*)o)[i] = x + y;
  }
}

// ======== pipelined GEMM mainloop (BM=128, BN=128, BK=64) ========
#define GEMM_MAINLOOP(Abase, lda, Wbase, ldw, Kdim)                          \
  auto stage = [&](int buf, int kt){                                         \
    _Pragma("unroll")                                                        \
    for (int i = 0; i < 4; ++i){                                             \
      int p = i*256 + tid; int row = p >> 3; int ch = (p & 7) ^ (row & 7);   \
      gload16(Abase + (size_t)(m0+row)*lda + kt + ch*8, &Als[buf][p*8]);     \
    }                                                                        \
    _Pragma("unroll")                                                        \
    for (int i = 0; i < 4; ++i){                                             \
      int p = i*256 + tid; int row = p >> 3; int ch = (p & 7) ^ (row & 7);   \
      gload16(Wbase + (size_t)(n0+row)*ldw + kt + ch*8, &Bls[buf][p*8]);     \
    }                                                                        \
  };                                                                         \
  stage(0, 0);                                                               \
  const int nk = Kdim >> 6;                                                  \
  for (int t = 0; t < nk; ++t){                                              \
    const int cur = t & 1;                                                   \
    if (t + 1 < nk){                                                         \
      stage(cur ^ 1, (t + 1) << 6);                                          \
      asm volatile("s_waitcnt vmcnt(8)" ::: "memory");                       \
    } else {                                                                 \
      asm volatile("s_waitcnt vmcnt(0)" ::: "memory");                       \
    }                                                                        \
    __builtin_amdgcn_s_barrier();                                            \
    __builtin_amdgcn_sched_barrier(0);                                       \
    __builtin_amdgcn_s_setprio(1);                                           \
    _Pragma("unroll")                                                        \
    for (int kk = 0; kk < 2; ++kk){                                          \
      half8v af[4], bf[4];                                                   \
      _Pragma("unroll")                                                      \
      for (int mi = 0; mi < 4; ++mi){                                        \
        int row = wr*64 + mi*16 + lr;                                        \
        int chp = (kk*4 + lg) ^ (row & 7);                                   \
        af[mi] = *(const half8v*)&Als[cur][row*64 + chp*8];                  \
      }                                                                      \
      _Pragma("unroll")                                                      \
      for (int ni = 0; ni < 4; ++ni){                                        \
        int row = wc*64 + ni*16 + lr;                                        \
        int chp = (kk*4 + lg) ^ (row & 7);                                   \
        bf[ni] = *(const half8v*)&Bls[cur][row*64 + chp*8];                  \
      }                                                                      \
      _Pragma("unroll")                                                      \
      for (int mi = 0; mi < 4; ++mi)                                         \
        _Pragma("unroll")                                                    \
        for (int ni = 0; ni < 4; ++ni)                                       \
          acc[mi][ni] = __builtin_amdgcn_mfma_f32_16x16x32_f16(              \
              af[mi], bf[ni], acc[mi][ni], 0, 0, 0);                         \
    }                                                                        \
    __builtin_amdgcn_s_setprio(0);                                           \
    asm volatile("s_waitcnt lgkmcnt(0)" ::: "memory");                       \
    __builtin_amdgcn_sched_barrier(0);                                       \
    __builtin_amdgcn_s_barrier();                                            \
  }

// ---------------- general GEMM (GAT path): fused row-dot --------------------
__global__ __launch_bounds__(256) void k_gemm_h(
    const h16* __restrict__ A, const h16* __restrict__ W,
    int lda, int ldw, int ldc, int K,
    const float* __restrict__ bias,
    h16* __restrict__ outh,
    const float* __restrict__ rdw, float* __restrict__ rdpart)
{
  __shared__ h16 Als[2][128*64];
  __shared__ h16 Bls[2][128*64];
  const int tid = threadIdx.x;
  const int gx = gridDim.x, gy = gridDim.y;
  const int wg = xcd_remap(blockIdx.x + gx * blockIdx.y, gx * gy);
  const int nidx = wg % gx;
  const int n0 = nidx * 128, m0 = (wg / gx) * 128;
  const int lane = tid & 63, wid = tid >> 6;
  const int wr = wid >> 1, wc = wid & 1;
  const int lr = lane & 15, lg = lane >> 4;
  f32x4 acc[4][4] = {};
  GEMM_MAINLOOP(A, lda, W, ldw, K)
  float rd[4][4] = {};
  #pragma unroll
  for (int mi = 0; mi < 4; ++mi){
    #pragma unroll
    for (int ni = 0; ni < 4; ++ni){
      int col = n0 + wc*64 + ni*16 + lr;
      int rowb = m0 + wr*64 + mi*16 + lg*4;
      float cb = bias[col];
      float aw = rdw ? rdw[col] : 0.f;
      #pragma unroll
      for (int r = 0; r < 4; ++r){
        size_t idx = (size_t)(rowb + r) * ldc + col;
        float v = acc[mi][ni][r] + cb;
        outh[idx] = (h16)v;
        if (rdw) rd[mi][r] += v * aw;
      }
    }
  }
  if (rdw){
    #pragma unroll
    for (int mi = 0; mi < 4; ++mi){
      #pragma unroll
      for (int r = 0; r < 4; ++r){
        float p = rd[mi][r];
        #pragma unroll
        for (int o = 1; o < 16; o <<= 1) p += __shfl_xor(p, o);
        if (lr == 0){
          int row = m0 + wr*64 + mi*16 + lg*4 + r;
          rdpart[(size_t)row * 12 + nidx*2 + wc] = p;
        }
      }
    }
  }
}

// ---------------- batched 2-way out-projection GEMM --------------------------
__global__ __launch_bounds__(256) void k_gemmop(
    const h16* __restrict__ A0, const h16* __restrict__ A1,
    const h16* __restrict__ W0, const h16* __restrict__ W1,
    const float* __restrict__ bb0, const float* __restrict__ bb1,
    h16* __restrict__ C0, h16* __restrict__ C1)
{
  __shared__ h16 Als[2][128*64];
  __shared__ h16 Bls[2][128*64];
  const int tid = threadIdx.x;
  const int gx = gridDim.x, gy = gridDim.y;   // 6, 64
  const int nwg = gx * gy * 2;
  const int wg = xcd_remap(blockIdx.x + gx*(blockIdx.y + gy*blockIdx.z), nwg);
  const int n0 = (wg % gx) * 128;
  const int m0 = ((wg / gx) % gy) * 128;
  const int bz = wg / (gx * gy);
  const h16* A = bz ? A1 : A0;
  const h16* W = bz ? W1 : W0;
  const float* bias = bz ? bb1 : bb0;
  h16* C = bz ? C1 : C0;
  const int lane = tid & 63, wid = tid >> 6;
  const int wr = wid >> 1, wc = wid & 1;
  const int lr = lane & 15, lg = lane >> 4;
  f32x4 acc[4][4] = {};
  GEMM_MAINLOOP(A, DD, W, DD, DD)
  #pragma unroll
  for (int mi = 0; mi < 4; ++mi){
    #pragma unroll
    for (int ni = 0; ni < 4; ++ni){
      int col = n0 + wc*64 + ni*16 + lr;
      int rowb = m0 + wr*64 + mi*16 + lg*4;
      float cb = bias[col];
      #pragma unroll
      for (int r = 0; r < 4; ++r)
        C[(size_t)(rowb + r) * DD + col] = (h16)(acc[mi][ni][r] + cb);
    }
  }
}

// ------ conv2 as overlapping-window GEMM over padded X (no im2col) ----------
__global__ __launch_bounds__(256) void k_conv2g(
    const h16* __restrict__ X, const h16* __restrict__ W,
    const float* __restrict__ sc, const float* __restrict__ off,
    h16* __restrict__ out)
{
  __shared__ h16 Als[2][128*64];
  __shared__ h16 Bls[2][128*64];
  const int tid = threadIdx.x;
  const int gx = gridDim.x, gy = gridDim.y;   // 6, 128
  const int wg = xcd_remap(blockIdx.x + gx * blockIdx.y, gx * gy);
  const int n0 = (wg % gx) * 128, m0 = (wg / gx) * 128;
  const int lane = tid & 63, wid = tid >> 6;
  const int wr = wid >> 1, wc = wid & 1;
  const int lr = lane & 15, lg = lane >> 4;
  f32x4 acc[4][4] = {};
  auto stage = [&](int buf, int kt){
    #pragma unroll
    for (int i = 0; i < 4; ++i){
      int p = i*256 + tid; int row = p >> 3; int ch = (p & 7) ^ (row & 7);
      int rm = m0 + row, b = rm >> 11, t = rm & 2047;
      gload16(X + (size_t)b*XROW + (size_t)t*128 + kt + ch*8, &Als[buf][p*8]);
    }
    #pragma unroll
    for (int i = 0; i < 4; ++i){
      int p = i*256 + tid; int row = p >> 3; int ch = (p & 7) ^ (row & 7);
      gload16(W + (size_t)(n0+row)*384 + kt + ch*8, &Bls[buf][p*8]);
    }
  };
  stage(0, 0);
  const int nk = 6;  // K=384
  for (int t = 0; t < nk; ++t){
    const int cur = t & 1;
    if (t + 1 < nk){
      stage(cur ^ 1, (t + 1) << 6);
      asm volatile("s_waitcnt vmcnt(8)" ::: "memory");
    } else {
      asm volatile("s_waitcnt vmcnt(0)" ::: "memory");
    }
    __builtin_amdgcn_s_barrier();
    __builtin_amdgcn_sched_barrier(0);
    __builtin_amdgcn_s_setprio(1);
    #pragma unroll
    for (int kk = 0; kk < 2; ++kk){
      half8v af[4], bf[4];
      #pragma unroll
      for (int mi = 0; mi < 4; ++mi){
        int row = wr*64 + mi*16 + lr;
        int chp = (kk*4 + lg) ^ (row & 7);
        af[mi] = *(const half8v*)&Als[cur][row*64 + chp*8];
      }
      #pragma unroll
      for (int ni = 0; ni < 4; ++ni){
        int row = wc*64 + ni*16 + lr;
        int chp = (kk*4 + lg) ^ (row & 7);
        bf[ni] = *(const half8v*)&Bls[cur][row*64 + chp*8];
      }
      #pragma unroll
      for (int mi = 0; mi < 4; ++mi)
        #pragma unroll
        for (int ni = 0; ni < 4; ++ni)
          acc[mi][ni] = __builtin_amdgcn_mfma_f32_16x16x32_f16(
              af[mi], bf[ni], acc[mi][ni], 0, 0, 0);
    }
    __builtin_amdgcn_s_setprio(0);
    asm volatile("s_waitcnt lgkmcnt(0)" ::: "memory");
    __builtin_amdgcn_sched_barrier(0);
    __builtin_amdgcn_s_barrier();
  }
  #pragma unroll
  for (int mi = 0; mi < 4; ++mi){
    #pragma unroll
    for (int ni = 0; ni < 4; ++ni){
      int col = n0 + wc*64 + ni*16 + lr;
      int rowb = m0 + wr*64 + mi*16 + lg*4;
      #pragma unroll
      for (int r = 0; r < 4; ++r){
        int rm = rowb + r, b = rm >> 11, t = rm & 2047;
        if (t < TLEN){
          float v = acc[mi][ni][r] * sc[col] + off[col];
          out[((size_t)b*TLEN + t)*DD + col] = (h16)gelu_f(v);
        }
      }
    }
  }
}

// ---------------- batched 6-way QKV projection GEMM --------------------------
__global__ __launch_bounds__(256) void k_gemm6(
    const h16* __restrict__ Lall, const h16* __restrict__ w6,
    const float* __restrict__ b1, const float* __restrict__ b2,
    h16* __restrict__ qkv6)
{
  __shared__ h16 Als[2][128*64];
  __shared__ h16 Bls[2][128*64];
  const int tid = threadIdx.x;
  const int gx = gridDim.x, gy = gridDim.y;   // 6, 64
  const int nwg = gx * gy * 6;
  const int wg = xcd_remap(blockIdx.x + gx*(blockIdx.y + gy*blockIdx.z), nwg);
  const int n0 = (wg % gx) * 128;
  const int m0 = ((wg / gx) % gy) * 128;
  const int bz = wg / (gx * gy);
  const int aidx = (1468 >> (2*bz)) & 3;      // {0,3,3,2,1,1}
  const h16* A = Lall + (size_t)aidx * SLOT;
  const h16* W = w6 + (size_t)bz * 589824;
  const float* bias = (bz < 3 ? b1 + bz*DD : b2 + (bz-3)*DD);
  h16* C = qkv6 + (size_t)bz * SLOT;
  const int lane = tid & 63, wid = tid >> 6;
  const int wr = wid >> 1, wc = wid & 1;
  const int lr = lane & 15, lg = lane >> 4;
  f32x4 acc[4][4] = {};
  GEMM_MAINLOOP(A, DD, W, DD, DD)
  #pragma unroll
  for (int mi = 0; mi < 4; ++mi){
    #pragma unroll
    for (int ni = 0; ni < 4; ++ni){
      int col = n0 + wc*64 + ni*16 + lr;
      int rowb = m0 + wr*64 + mi*16 + lg*4;
      float cb = bias[col];
      #pragma unroll
      for (int r = 0; r < 4; ++r)
        C[(size_t)(rowb + r) * DD + col] = (h16)(acc[mi][ni][r] + cb);
    }
  }
}

// ------- merged V transpose: z = which*32 + bh ------------------------------
__global__ __launch_bounds__(256) void k_trV(const h16* __restrict__ V0,
    const h16* __restrict__ V1, h16* __restrict__ VT0, h16* __restrict__ VT1){
  __shared__ h16 tile[64*64];
  const int zz = blockIdx.z;
  const int which = zz >> 5, bh = zz & 31;
  const int b = bh >> 2, h = bh & 3;
  const h16* Vh = which ? V1 : V0;
  h16* VT = which ? VT1 : VT0;
  const int q0 = blockIdx.x * 64, d0 = blockIdx.y * 64;
  const int t = threadIdx.x;
  {
    int qq = t >> 2, ds = (t & 3) * 16;
    const h16* src = Vh + ((size_t)b*NSEQ + q0 + qq)*DD + h*HDIM + d0 + ds;
    half8v v0 = *(const half8v*)src;
    half8v v1 = *(const half8v*)(src + 8);
    int c0 = (ds >> 3) ^ (qq & 7), c1 = ((ds >> 3) + 1) ^ (qq & 7);
    *(half8v*)&tile[qq*64 + c0*8] = v0;
    *(half8v*)&tile[qq*64 + c1*8] = v1;
  }
  __syncthreads();
  {
    int dd = t >> 2, qs = (t & 3) * 16;
    half8v o0, o1;
    #pragma unroll
    for (int j = 0; j < 8; ++j){
      int q = qs + j, q2 = qs + 8 + j;
      o0[j] = tile[q*64  + (((dd>>3) ^ (q&7))*8)  + (dd & 7)];
      o1[j] = tile[q2*64 + (((dd>>3) ^ (q2&7))*8) + (dd & 7)];
    }
    h16* dst = VT + (size_t)bh*HDIM*NSEQ + (size_t)(d0+dd)*NSEQ + q0 + qs;
    *(half8v*)dst = o0;
    *(half8v*)(dst + 8) = o1;
  }
}

// ------- merged flash attention: 2 q-tiles/block, prescaled-Q exp2 -----------
// grid (32 bh, 8 qt, 2 mha): each block processes q-tiles qt and qt+8 against
// one K/V stream (halves staging; grid 512 = exact CU fill, no tail).
__global__ __launch_bounds__(256, 2) void k_flash(
    const h16* __restrict__ Q0, const h16* __restrict__ K0,
    const h16* __restrict__ T0, h16* __restrict__ O0,
    const h16* __restrict__ Q1, const h16* __restrict__ K1,
    const h16* __restrict__ T1, h16* __restrict__ O1){
  __shared__ h16 Ks[2][32*192];
  __shared__ h16 Vs[2][192*32];
  __shared__ h16 Ps[4][16*32];
  const int tid = threadIdx.x;
  const int bh = blockIdx.x, qt = blockIdx.y, which = blockIdx.z;
  const int b = bh >> 2, h = bh & 3;
  const int q0a = qt * 64, q0b = (qt + 8) * 64;
  const h16* Qp = which ? Q1 : Q0;
  const h16* Kp = which ? K1 : K0;
  const h16* VTp = which ? T1 : T0;
  h16* Op = which ? O1 : O0;
  const h16* Qg = Qp + (size_t)b*NSEQ*DD + h*HDIM;
  const h16* Kg = Kp + (size_t)b*NSEQ*DD + h*HDIM;
  const h16* Vg = VTp + (size_t)bh*HDIM*NSEQ;
  const int lane = tid & 63, wid = tid >> 6;
  const int lr = lane & 15, lg = lane >> 4;
  const float SC2 = 0.07216878364870322f * 1.4426950408889634f;  // /sqrt(192)*log2e
  half8v qfa[6], qfb[6];
  {
    const h16 qs2 = (h16)SC2;
    int qra = q0a + wid*16 + lr, qrb = q0b + wid*16 + lr;
    #pragma unroll
    for (int ks = 0; ks < 6; ++ks){
      half8v va = *(const half8v*)(Qg + (size_t)qra*DD + ks*32 + lg*8);
      half8v vb = *(const half8v*)(Qg + (size_t)qrb*DD + ks*32 + lg*8);
      #pragma unroll
      for (int j = 0; j < 8; ++j){ va[j] = va[j] * qs2; vb[j] = vb[j] * qs2; }
      qfa[ks] = va; qfb[ks] = vb;
    }
  }
  auto stageK = [&](int buf, int k0){
    #pragma unroll
    for (int i = 0; i < 3; ++i){
      int p = i*256 + tid;
      int row = p / 24, chp = p % 24;
      int ch = chp ^ (row & 7);
      gload16(Kg + (size_t)(k0+row)*DD + ch*8, &Ks[buf][p*8]);
    }
  };
  auto stageV = [&](int buf, int k0){
    #pragma unroll
    for (int i = 0; i < 3; ++i){
      int p = i*256 + tid;
      int row = p >> 2, chp = p & 3;
      int ch = chp ^ ((row >> 1) & 3);
      gload16(Vg + (size_t)row*NSEQ + k0 + ch*8, &Vs[buf][p*8]);
    }
  };
  stageK(0, 0); stageV(0, 0);
  f32x4 oacca[12] = {}, oaccb[12] = {};
  f32x4 osuma = {0.f, 0.f, 0.f, 0.f}, osumb = {0.f, 0.f, 0.f, 0.f};
  float m2a[4] = {-1e30f, -1e30f, -1e30f, -1e30f};
  float m2b[4] = {-1e30f, -1e30f, -1e30f, -1e30f};
  half8v vone;
  #pragma unroll
  for (int j = 0; j < 8; ++j) vone[j] = (h16)1.f;

  auto process = [&](half8v (&qf)[6], f32x4 (&oacc)[12], f32x4 &osum,
                     float (&m2)[4], int cur){
    f32x4 sacc[2] = {};
    __builtin_amdgcn_s_setprio(1);
    #pragma unroll
    for (int ks = 0; ks < 6; ++ks){
      #pragma unroll
      for (int t = 0; t < 2; ++t){
        int krow = t*16 + lr;
        int ch = (ks*4 + lg) ^ (krow & 7);
        half8v kf = *(const half8v*)&Ks[cur][krow*192 + ch*8];
        sacc[t] = __builtin_amdgcn_mfma_f32_16x16x32_f16(qf[ks], kf, sacc[t], 0, 0, 0);
      }
    }
    __builtin_amdgcn_s_setprio(0);
    float lmaxr[4];
    #pragma unroll
    for (int r = 0; r < 4; ++r) lmaxr[r] = fmaxf(sacc[0][r], sacc[1][r]);
    bool flag = false;
    #pragma unroll
    for (int r = 0; r < 4; ++r) flag |= (lmaxr[r] > m2[r] + 14.f);
    if (__ballot(flag)){
      float c[4];
      #pragma unroll
      for (int r = 0; r < 4; ++r){
        float mt = lmaxr[r];
        #pragma unroll
        for (int off = 1; off < 16; off <<= 1) mt = fmaxf(mt, __shfl_xor(mt, off));
        if (mt > m2[r]){ c[r] = exp2f(m2[r] - mt); m2[r] = mt; }
        else c[r] = 1.f;
      }
      #pragma unroll
      for (int dt = 0; dt < 12; ++dt){
        f32x4 o = oacc[dt];
        o[0] *= c[0]; o[1] *= c[1]; o[2] *= c[2]; o[3] *= c[3];
        oacc[dt] = o;
      }
      osum[0] *= c[0]; osum[1] *= c[1]; osum[2] *= c[2]; osum[3] *= c[3];
    }
    #pragma unroll
    for (int t = 0; t < 2; ++t){
      #pragma unroll
      for (int r = 0; r < 4; ++r){
        float p = exp2f(sacc[t][r] - m2[r]);
        int q = lg*4 + r, key = t*16 + lr;
        int ch = (t*2 + (lr>>3)) ^ ((q>>1) & 3);
        Ps[wid][q*32 + ch*8 + (key & 7)] = (h16)p;
      }
    }
    asm volatile("s_waitcnt lgkmcnt(0)" ::: "memory");   // own-wave P writes done
    __builtin_amdgcn_sched_barrier(0);
    {
      int pch = lg ^ ((lr >> 1) & 3);
      half8v pf = *(const half8v*)&Ps[wid][lr*32 + pch*8];
      __builtin_amdgcn_s_setprio(1);
      #pragma unroll
      for (int dt = 0; dt < 12; ++dt){
        int drow = dt*16 + lr;
        int vch = lg ^ ((drow >> 1) & 3);
        half8v vf = *(const half8v*)&Vs[cur][drow*32 + vch*8];
        oacc[dt] = __builtin_amdgcn_mfma_f32_16x16x32_f16(pf, vf, oacc[dt], 0, 0, 0);
      }
      osum = __builtin_amdgcn_mfma_f32_16x16x32_f16(pf, vone, osum, 0, 0, 0);
      __builtin_amdgcn_s_setprio(0);
    }
    asm volatile("s_waitcnt lgkmcnt(0)" ::: "memory");   // Ps/LDS reads retired
    __builtin_amdgcn_sched_barrier(0);
  };

  for (int kt = 0; kt < 32; ++kt){
    const int cur = kt & 1;
    if (kt + 1 < 32){
      stageK(cur^1, (kt+1)*32); stageV(cur^1, (kt+1)*32);
      asm volatile("s_waitcnt vmcnt(6)" ::: "memory");
    } else {
      asm volatile("s_waitcnt vmcnt(0)" ::: "memory");
    }
    __builtin_amdgcn_s_barrier();
    __builtin_amdgcn_sched_barrier(0);
    process(qfa, oacca, osuma, m2a, cur);   // ends with lgkmcnt(0): Ps reusable
    process(qfb, oaccb, osumb, m2b, cur);
    __builtin_amdgcn_s_barrier();            // all reads of cur done
  }
  {
    float inv[4];
    #pragma unroll
    for (int r = 0; r < 4; ++r) inv[r] = 1.0f / osuma[r];
    h16* Og = Op + (size_t)b*NSEQ*DD + h*HDIM;
    #pragma unroll
    for (int dt = 0; dt < 12; ++dt){
      #pragma unroll
      for (int r = 0; r < 4; ++r){
        int q = q0a + wid*16 + lg*4 + r;
        Og[(size_t)q*DD + dt*16 + lr] = (h16)(oacca[dt][r] * inv[r]);
      }
    }
    #pragma unroll
    for (int r = 0; r < 4; ++r) inv[r] = 1.0f / osumb[r];
    #pragma unroll
    for (int dt = 0; dt < 12; ++dt){
      #pragma unroll
      for (int r = 0; r < 4; ++r){
        int q = q0b + wid*16 + lg*4 + r;
        Og[(size_t)q*DD + dt*16 + lr] = (h16)(oaccb[dt][r] * inv[r]);
      }
    }
  }
}

// -------- fused GAT softmax + ctx stage1: alpha computed per-block ----------
__global__ __launch_bounds__(256) void k_ctxs(const float* __restrict__ rdpart,
    const h16* __restrict__ h, float* __restrict__ part){
  __shared__ float red[4];
  __shared__ float al[64];
  const int tid = threadIdx.x;
  const int b = blockIdx.y, pc = blockIdx.z;
  float v[4]; float mx = -1e30f;
  #pragma unroll
  for (int j = 0; j < 4; ++j){
    int i = j * 256 + tid;
    const float* p = rdpart + (size_t)(b * NSEQ + i) * 12;
    float s = 0.f;
    #pragma unroll
    for (int k = 0; k < 12; ++k) s += p[k];
    v[j] = s; mx = fmaxf(mx, s);
  }
  mx = wave_max(mx);
  if ((tid & 63) == 0) red[tid >> 6] = mx;
  __syncthreads();
  mx = fmaxf(fmaxf(red[0], red[1]), fmaxf(red[2], red[3]));
  __syncthreads();
  float s = 0.f;
  #pragma unroll
  for (int j = 0; j < 4; ++j){ v[j] = __expf(v[j] - mx); s += v[j]; }
  s = wave_sum(s);
  if ((tid & 63) == 0) red[tid >> 6] = s;
  __syncthreads();
  s = red[0] + red[1] + red[2] + red[3];
  float inv = 1.0f / s;
  #pragma unroll
  for (int j = 0; j < 4; ++j){
    int i = j * 256 + tid;
    int rel = i - pc * 64;
    if (rel >= 0 && rel < 64) al[rel] = v[j] * inv;
  }
  __syncthreads();
  int d = blockIdx.x * 256 + tid;
  float acc = 0.f;
  const h16* hp = h + ((size_t)b * NSEQ + pc * 64) * DD + d;
  #pragma unroll 4
  for (int j = 0; j < 64; ++j) acc += al[j] * (float)hp[(size_t)j * DD];
  part[(size_t)(b * 16 + pc) * DD + d] = acc;
}

__global__ __launch_bounds__(256) void k_ctx2(const float* __restrict__ part,
    float scale, float* __restrict__ ctx){
  int d = blockIdx.x * 256 + threadIdx.x;
  int b = blockIdx.y;
  if (d >= DD) return;
  float acc = 0.f;
  #pragma unroll
  for (int p = 0; p < 16; ++p) acc += part[(size_t)(b * 16 + p) * DD + d];
  ctx[b * DD + d] = acc * scale;
}

__global__ __launch_bounds__(256) void k_pool1(const h16* __restrict__ x,
    float* __restrict__ part){
  int d = blockIdx.x * 256 + threadIdx.x;
  int b = blockIdx.y, pc = blockIdx.z;
  if (d >= DD) return;
  float acc = 0.f;
  const h16* xp = x + ((size_t)b * NSEQ + pc * 64) * DD + d;
  #pragma unroll 4
  for (int j = 0; j < 64; ++j) acc += (float)xp[(size_t)j * DD];
  part[(size_t)(b * 16 + pc) * DD + d] = acc;
}

__global__ __launch_bounds__(128) void k_clf(const float* __restrict__ pooled,
    const float* __restrict__ w1, const float* __restrict__ b1,
    const float* __restrict__ w2, const float* __restrict__ b2,
    float* __restrict__ out){
  __shared__ float pl[DD];
  __shared__ float h1[128];
  int b = blockIdx.x, tid = threadIdx.x;
  #pragma unroll
  for (int j = 0; j < 6; ++j) pl[j * 128 + tid] = pooled[b * DD + j * 128 + tid];
  __syncthreads();
  float acc = b1[tid];
  const float* wp = w1 + (size_t)tid * DD;
  for (int d = 0; d < DD; ++d) acc += pl[d] * wp[d];
  h1[tid] = gelu_f(acc);
  __syncthreads();
  if (tid < 2){
    float o = b2[tid];
    const float* w2p = w2 + tid * 128;
    for (int c = 0; c < 128; ++c) o += h1[c] * w2p[c];
    out[b * 2 + tid] = o;
  }
}

// =========================== launcher ===========================
extern "C" void kernel_launch(void* const* d_in, const int* in_sizes, int n_in,
                              void* d_out, int out_size, void* d_ws, size_t ws_size,
                              hipStream_t stream){
  (void)in_sizes; (void)n_in; (void)out_size;
  const float* w2v      = (const float*)d_in[0];
  const float* cqcc     = (const float*)d_in[1];
  const float* conv1_w  = (const float*)d_in[2];
  const float* conv1_b  = (const float*)d_in[3];
  const float* bn1_g    = (const float*)d_in[4];
  const float* bn1_b    = (const float*)d_in[5];
  const float* bn1_m    = (const float*)d_in[6];
  const float* bn1_v    = (const float*)d_in[7];
  const float* conv2_w  = (const float*)d_in[8];
  const float* conv2_b  = (const float*)d_in[9];
  const float* bn2_g    = (const float*)d_in[10];
  const float* bn2_b    = (const float*)d_in[11];
  const float* bn2_m    = (const float*)d_in[12];
  const float* bn2_v    = (const float*)d_in[13];
  const float* pos_embed= (const float*)d_in[14];
  const float* lnq_g    = (const float*)d_in[15];
  const float* lnq_b    = (const float*)d_in[16];
  const float* lnkv_g   = (const float*)d_in[17];
  const float* lnkv_b   = (const float*)d_in[18];
  const float* a1_in_w  = (const float*)d_in[19];
  const float* a1_in_b  = (const float*)d_in[20];
  const float* a1_out_w = (const float*)d_in[21];
  const float* a1_out_b = (const float*)d_in[22];
  const float* a2_in_w  = (const float*)d_in[23];
  const float* a2_in_b  = (const float*)d_in[24];
  const float* a2_out_w = (const float*)d_in[25];
  const float* a2_out_b = (const float*)d_in[26];
  const float* gat_fc_w = (const float*)d_in[27];
  const float* gat_fc_b = (const float*)d_in[28];
  const float* gat_a_w  = (const float*)d_in[29];
  // d_in[30] gat_a_b: cancels in softmax over j — unused.
  const float* gln_g    = (const float*)d_in[31];
  const float* gln_b    = (const float*)d_in[32];
  const float* clf_w1   = (const float*)d_in[33];
  const float* clf_b1   = (const float*)d_in[34];
  const float* clf_w2   = (const float*)d_in[35];
  const float* clf_b2   = (const float*)d_in[36];

  char* wsp = (char*)d_ws;
  auto F = [&](size_t bytes){ char* p = wsp; wsp += (bytes + 255) & ~(size_t)255; return p; };
  h16* xh      = (h16*)F(12582912);       // GAT running state (f16)
  h16* Lall    = (h16*)F(4*12582912);     // LN slots 0..3; also conv X buffer
  h16* qkv6    = (h16*)F(6*12582912);     // Q1 K1 V1 Q2 K2 V2; also x2h f16
  h16* VT      = (h16*)F(12582912);
  h16* VT2     = (h16*)F(12582912);
  h16* o1h     = (h16*)F(12582912);
  h16* o2h     = (h16*)F(12582912);
  h16* w6      = (h16*)F(2*3538944);      // Wqkv1 | Wqkv2
  h16* w_a1out = (h16*)F(1179648);
  h16* w_a2out = (h16*)F(1179648);
  h16* w_gat   = (h16*)F(3538944);
  h16* w_c2    = (h16*)F(589824);
  float* scb   = (float*)F(3072);
  float* offb  = (float*)F(3072);
  float* ctxb  = (float*)F(24576);
  float* pooled= (float*)F(24576);
  float* partb = (float*)F(393216);       // rowdot 8192x12 f32 / pool partials
  float* partc = (float*)F(393216);       // ctx partials 8x16x768 f32
  if ((size_t)(wsp - (char*)d_ws) > ws_size) return;

  h16* X   = Lall;                        // padded conv buffer [8][2002][128]
  h16* x2h = qkv6;                        // conv2 out f16 (24.6 MB, slots 0-1)
  h16* hh  = qkv6;                        // GAT h (slot0, dead after outproj)

  const int NR = BBATCH * NSEQ;           // 8192

  // --- merged weight casts + conv2 permute-cast + bn prep ---
  {
    CastArgs ca;
    ca.s[0]=a1_in_w;  ca.d[0]=w6;            int n0=1769472;
    ca.s[1]=a2_in_w;  ca.d[1]=w6+1769472;    int n1=1769472;
    ca.s[2]=a1_out_w; ca.d[2]=w_a1out;       int n2=589824;
    ca.s[3]=a2_out_w; ca.d[3]=w_a2out;       int n3=589824;
    ca.s[4]=gat_fc_w; ca.d[4]=w_gat;         int n4=1769472;
    ca.cum[0]=0; ca.cum[1]=n0; ca.cum[2]=n0+n1; ca.cum[3]=n0+n1+n2;
    ca.cum[4]=n0+n1+n2+n3; ca.cum[5]=n0+n1+n2+n3+n4;
    int total = ca.cum[5];
    k_cast5<<<(total+255)/256, 256, 0, stream>>>(ca, total);
  }
  k_castc2<<<(294912+255)/256, 256, 0, stream>>>(conv2_w, w_c2);
  k_bnprep<<<3, 256, 0, stream>>>(conv2_b, bn2_g, bn2_b, bn2_m, bn2_v, scb, offb);

  // --- front-end convs (no im2col) ---
  k_conv1t<<<dim3(8, 4, BBATCH), 256, 0, stream>>>(cqcc, conv1_w, conv1_b,
      bn1_g, bn1_b, bn1_m, bn1_v, X);
  k_conv2g<<<dim3(6, 128), 256, 0, stream>>>(X, w_c2, scb, offb, x2h);

  // --- fused interp/addpos + dual LN (slots 0..3) ---
  k_interp_ln<<<NR, 256, 0, stream>>>(x2h, pos_embed,
      lnq_g, lnq_b, Lall, lnkv_g, lnkv_b, Lall + SLOT);
  k_addpos_ln<<<NR, 256, 0, stream>>>(w2v, pos_embed,
      lnq_g, lnq_b, Lall + 2*SLOT, lnkv_g, lnkv_b, Lall + 3*SLOT);

  // --- all six QKV projections in one dispatch ---
  k_gemm6<<<dim3(6, 64, 6), 256, 0, stream>>>(Lall, w6, a1_in_b, a2_in_b, qkv6);

  // ================= both MHAs, merged =================
  k_trV<<<dim3(16, 3, 64), 256, 0, stream>>>(qkv6 + 2*(size_t)SLOT,
      qkv6 + 5*(size_t)SLOT, VT, VT2);
  k_flash<<<dim3(32, 8, 2), 256, 0, stream>>>(
      qkv6, qkv6 + (size_t)SLOT, VT, qkv6,                        // MHA1: O1 -> slot0
      qkv6 + 3*(size_t)SLOT, qkv6 + 4*(size_t)SLOT, VT2,
      qkv6 + 3*(size_t)SLOT);                                     // MHA2: O2 -> slot3
  k_gemmop<<<dim3(6, 64, 2), 256, 0, stream>>>(
      qkv6, qkv6 + 3*(size_t)SLOT, w_a1out, w_a2out,
      a1_out_b, a2_out_b, o1h, o2h);
  k_addh<<<(NR*DD/8 + 255)/256, 256, 0, stream>>>(o1h, o2h, xh, NR*DD/8);

  // ================= GAT x3 (rowdot fused; softmax fused into ctx) ==========
  for (int l = 0; l < 3; ++l){
    k_gemm_h<<<dim3(6, 64), 256, 0, stream>>>(xh, w_gat + (size_t)l*589824,
        DD, DD, DD, DD, gat_fc_b + l*DD, hh, gat_a_w + l*2*DD + DD, partb);
    k_ctxs<<<dim3(3, BBATCH, 16), 256, 0, stream>>>(partb, hh, partc);
    k_ctx2<<<dim3(3, BBATCH), 256, 0, stream>>>(partc, 1.0f, ctxb);
    k_lnH<<<NR, 256, 0, stream>>>(xh, ctxb, gln_g + l*DD, gln_b + l*DD, xh);
  }

  k_pool1<<<dim3(3, BBATCH, 16), 256, 0, stream>>>(xh, partb);
  k_ctx2<<<dim3(3, BBATCH), 256, 0, stream>>>(partb, 1.0f/NSEQ, pooled);
  k_clf<<<BBATCH, 128, 0, stream>>>(pooled, clf_w1, clf_b1, clf_w2, clf_b2,
                                    (float*)d_out);
}